// Round 3
// baseline (1195.737 us; speedup 1.0000x reference)
//
#include <hip/hip_runtime.h>
#include <hip/hip_bf16.h>
#include <math.h>

using bf16 = __hip_bfloat16;
typedef __attribute__((ext_vector_type(8))) short s8v;
typedef __attribute__((ext_vector_type(4))) float f32x4;

#define D_MODEL 1024
#define NB 8
#define SEQ 1024
#define NHEAD 16
#define HD 64
#define MOE_H 2048
#define TOKENS (NB*SEQ)
#define QKV_S 3072   // fused QKV row stride

// ---------------- fp32 -> bf16 convert ----------------
__global__ void f2b_k(const float* __restrict__ in, bf16* __restrict__ out, int n) {
    int i = blockIdx.x * blockDim.x + threadIdx.x;
    int stride = gridDim.x * blockDim.x;
    for (; i < n; i += stride) out[i] = __float2bfloat16(in[i]);
}

// concat 3x1024 bias vectors into one 3072 buffer
__global__ void cat3_k(const float* __restrict__ a, const float* __restrict__ b,
                       const float* __restrict__ c, float* __restrict__ o) {
    int i = blockIdx.x * blockDim.x + threadIdx.x;
    if (i < 1024) o[i] = a[i];
    else if (i < 2048) o[i] = b[i - 1024];
    else if (i < 3072) o[i] = c[i - 2048];
}

// ---------------- decomposition: trend + seasonal (LDS-tiled stencil) ----------------
#define TN 128
#define TD 64
__global__ __launch_bounds__(256) void decomp_k(
    const float* __restrict__ x, const float* __restrict__ alpha,
    const float* __restrict__ dw7, const float* __restrict__ dw25,
    const float* __restrict__ dw49, float* __restrict__ Tr, float* __restrict__ S)
{
    __shared__ float xs[TN + 48][TD];
    const int n0 = blockIdx.x * TN, d0 = blockIdx.y * TD, b = blockIdx.z;
    for (int i = threadIdx.x; i < (TN + 48) * (TD / 4); i += 256) {
        int r = i / (TD / 4), c4 = (i % (TD / 4)) * 4;
        int n = n0 + r - 24;
        if (n < 0) n = -n;
        if (n > SEQ - 1) n = 2 * (SEQ - 1) - n;
        *(float4*)&xs[r][c4] =
            *(const float4*)&x[((size_t)(b * SEQ + n)) * D_MODEL + d0 + c4];
    }
    float a0 = alpha[0], a1 = alpha[1], a2 = alpha[2];
    float mx = fmaxf(a0, fmaxf(a1, a2));
    float e0 = __expf(a0 - mx), e1 = __expf(a1 - mx), e2 = __expf(a2 - mx);
    float inv = 1.0f / (e0 + e1 + e2);
    float w7 = e0 * inv, w25 = e1 * inv, w49 = e2 * inv;
    const int dl = threadIdx.x & 63;
    const int nt = threadIdx.x >> 6;
    const int d = d0 + dl;
    float w[49];
    #pragma unroll
    for (int j = 0; j < 49; j++) {
        float v = w49 * dw49[d * 49 + j];
        if (j >= 12 && j < 37) v += w25 * dw25[d * 25 + j - 12];
        if (j >= 21 && j < 28) v += w7 * dw7[d * 7 + j - 21];
        w[j] = v;
    }
    __syncthreads();
    for (int nl = nt; nl < TN; nl += 4) {
        float acc = 0.f;
        #pragma unroll
        for (int j = 0; j < 49; j++) acc = fmaf(xs[nl + j][dl], w[j], acc);
        size_t idx = ((size_t)(b * SEQ + n0 + nl)) * D_MODEL + d;
        Tr[idx] = acc;
        S[idx] = xs[nl + 24][dl] - acc;
    }
}

// ---------------- LayerNorm (fp32 in, bf16 out, optional fp32 out) ----------------
__global__ __launch_bounds__(256) void ln_k(
    const float* __restrict__ x, const float* __restrict__ g, const float* __restrict__ b,
    bf16* __restrict__ ob, float* __restrict__ of)
{
    int row = blockIdx.x, t = threadIdx.x;
    const float* xr = x + (size_t)row * D_MODEL;
    float s = 0.f, s2 = 0.f;
    for (int d = t; d < D_MODEL; d += 256) { float v = xr[d]; s += v; s2 += v * v; }
    #pragma unroll
    for (int o = 32; o > 0; o >>= 1) { s += __shfl_down(s, o); s2 += __shfl_down(s2, o); }
    __shared__ float sh[8];
    int wid = t >> 6, lane = t & 63;
    if (lane == 0) { sh[wid] = s; sh[4 + wid] = s2; }
    __syncthreads();
    if (t == 0) {
        float ts = sh[0] + sh[1] + sh[2] + sh[3];
        float t2 = sh[4] + sh[5] + sh[6] + sh[7];
        float m = ts / D_MODEL;
        float var = t2 / D_MODEL - m * m;
        sh[0] = m; sh[1] = rsqrtf(var + 1e-5f);
    }
    __syncthreads();
    float m = sh[0], rs = sh[1];
    for (int d = t; d < D_MODEL; d += 256) {
        float v = (xr[d] - m) * rs * g[d] + b[d];
        ob[(size_t)row * D_MODEL + d] = __float2bfloat16(v);
        if (of) of[(size_t)row * D_MODEL + d] = v;
    }
}

// ---------------- bf16 MFMA GEMM: C[M,O] = A[M,K] @ B[O,K]^T (+bias)(+act) ----------------
// OMODE 0: fp32 out (+resid), 1: bf16 out, 2: fp32 accumulate += rowscale*v
// GMODE 0: dense; 1: gather A rows via row_map (store compact); 2: scatter store via row_map
// reg-staged into padded LDS (conflict-free ds_reads; measured-best at these short-K shapes)
template<int ACT, int OMODE, int GMODE>
__global__ __launch_bounds__(256) void gemm_nt(
    const bf16* __restrict__ A, const bf16* __restrict__ B,
    const float* __restrict__ bias, const float* resid,
    const float* __restrict__ rowscale, int rs_stride,
    void* C, int M, int K, int O,
    const int* __restrict__ row_map, const int* __restrict__ cnt_ptr)
{
    const int bm = blockIdx.x, bn = blockIdx.y;
    int M_act = M;
    if (GMODE != 0) {
        M_act = *cnt_ptr;
        if (bm * 128 >= M_act) return;
    }
    __shared__ bf16 As[128][72];
    __shared__ bf16 Bs[128][72];
    const int t = threadIdx.x;
    const int lane = t & 63, wid = t >> 6;
    const int wm = wid >> 1, wn = wid & 1;
    f32x4 acc[4][4] = {};
    const int lr = t >> 3;
    const int lc = (t & 7) * 8;
    const size_t abase = (size_t)(bm * 128) * K;
    const size_t bbase = (size_t)(bn * 128) * K;
    int amap[4];
    if (GMODE == 1) {
        #pragma unroll
        for (int p = 0; p < 4; p++) {
            int gr = bm * 128 + p * 32 + lr;
            amap[p] = row_map[gr < M_act ? gr : M_act - 1];
        }
    }
    for (int k0 = 0; k0 < K; k0 += 64) {
        #pragma unroll
        for (int p = 0; p < 4; p++) {
            int r = p * 32 + lr;
            size_t arow = (GMODE == 1) ? (size_t)amap[p] * K : abase + (size_t)r * K;
            *(s8v*)&As[r][lc] = *(const s8v*)&A[arow + k0 + lc];
            *(s8v*)&Bs[r][lc] = *(const s8v*)&B[bbase + (size_t)r * K + k0 + lc];
        }
        __syncthreads();
        const int fr = lane & 15, fq = (lane >> 4) * 8;
        #pragma unroll
        for (int kk = 0; kk < 64; kk += 32) {
            s8v af[4], bfr[4];
            #pragma unroll
            for (int i = 0; i < 4; i++) {
                af[i]  = *(const s8v*)&As[wm * 64 + i * 16 + fr][kk + fq];
                bfr[i] = *(const s8v*)&Bs[wn * 64 + i * 16 + fr][kk + fq];
            }
            #pragma unroll
            for (int i = 0; i < 4; i++)
                #pragma unroll
                for (int j = 0; j < 4; j++)
                    acc[i][j] = __builtin_amdgcn_mfma_f32_16x16x32_bf16(af[i], bfr[j], acc[i][j], 0, 0, 0);
        }
        __syncthreads();
    }
    const int cr = lane & 15, quad = lane >> 4;
    #pragma unroll
    for (int i = 0; i < 4; i++) {
        #pragma unroll
        for (int r = 0; r < 4; r++) {
            int row = bm * 128 + wm * 64 + i * 16 + quad * 4 + r;
            if (GMODE != 0 && row >= M_act) continue;
            int srow = (GMODE == 2) ? row_map[row] : row;
            #pragma unroll
            for (int j = 0; j < 4; j++) {
                int col = bn * 128 + wn * 64 + j * 16 + cr;
                float v = acc[i][j][r];
                if (bias) v += bias[col];
                if (ACT == 1) v = 0.5f * v * (1.0f + erff(v * 0.70710678118f));
                size_t idx = (size_t)srow * O + col;
                if (OMODE == 0) {
                    float rv = resid ? resid[idx] : 0.0f;
                    ((float*)C)[idx] = rv + v;
                } else if (OMODE == 1) {
                    ((bf16*)C)[idx] = __float2bfloat16(v);
                } else {
                    ((float*)C)[idx] += rowscale[(size_t)srow * rs_stride] * v;
                }
            }
        }
    }
}

// ---------------- MFMA flash attention with ALiBi, fixed-shift softmax ----------------
// block: 256 thr = 4 waves, each wave owns 32 q-rows (128 q-rows/block)
// reads packed QKV [tokens, 3072]; T14 async-stage; log2-domain softmax; setprio on MFMA
__global__ __launch_bounds__(256) void attn_k(
    const bf16* __restrict__ QKV, bf16* __restrict__ Y)
{
    __shared__ bf16 Ks[64][72];
    __shared__ bf16 Vt[64][66];
    __shared__ bf16 Pw[4][32][72];
    const int t = threadIdx.x;
    const int wave = t >> 6, lane = t & 63;
    const int qm = lane & 15, quad = lane >> 4;
    const int b = blockIdx.z, h = blockIdx.y;
    const int qbase = blockIdx.x * 128 + wave * 32;
    const float LOG2E = 1.44269504f;
    const float slope2 = exp2f(-0.5f * (float)(h + 1)) * LOG2E;   // slope * log2(e)
    const float NEG8L2 = -11.54156036f;                            // -8 * log2(e)
    const float SCL2   = 0.18033688f;                              // 0.125 * log2(e)

    s8v qa[2][2];
    #pragma unroll
    for (int g = 0; g < 2; g++) {
        const bf16* qp = QKV + ((size_t)(b * SEQ + qbase + g * 16 + qm)) * QKV_S + h * HD;
        qa[g][0] = *(const s8v*)&qp[quad * 8];
        qa[g][1] = *(const s8v*)&qp[32 + quad * 8];
    }
    float aqp[2][4];
    #pragma unroll
    for (int g = 0; g < 2; g++)
        #pragma unroll
        for (int r = 0; r < 4; r++)
            aqp[g][r] = slope2 * (float)(qbase + g * 16 + quad * 4 + r) + NEG8L2;

    f32x4 o[2][4] = {};
    float l[2][4] = {};

    const int sr = t >> 2;
    const int scc = (t & 3) * 16;
    // base for this lane's K row slice; V is +1024 from K within the packed row
    const bf16* kvb = QKV + (size_t)(b * SEQ) * QKV_S + D_MODEL + h * HD + scc;

    // prologue: load tile 0 into regs
    {
        const bf16* p0 = kvb + (size_t)sr * QKV_S;
        s8v t0 = *(const s8v*)&p0[0];
        s8v t1 = *(const s8v*)&p0[8];
        s8v t2 = *(const s8v*)&p0[D_MODEL];
        s8v t3 = *(const s8v*)&p0[D_MODEL + 8];
        // fallthrough into loop-carried regs
        s8v k0v = t0, k1v = t1, v0 = t2, v1 = t3;

        for (int k0 = 0; k0 < SEQ; k0 += 64) {
            *(s8v*)&Ks[sr][scc] = k0v;
            *(s8v*)&Ks[sr][scc + 8] = k1v;
            #pragma unroll
            for (int j = 0; j < 8; j++) {
                Vt[scc + j][sr]     = ((const bf16*)&v0)[j];
                Vt[scc + 8 + j][sr] = ((const bf16*)&v1)[j];
            }
            __syncthreads();
            if (k0 + 64 < SEQ) {   // T14: issue next tile's loads; latency hides under compute
                const bf16* np = kvb + (size_t)(k0 + 64 + sr) * QKV_S;
                k0v = *(const s8v*)&np[0];
                k1v = *(const s8v*)&np[8];
                v0  = *(const s8v*)&np[D_MODEL];
                v1  = *(const s8v*)&np[D_MODEL + 8];
            }
            float bk[4];
            #pragma unroll
            for (int jt = 0; jt < 4; jt++) bk[jt] = slope2 * (float)(k0 + jt * 16 + qm);
            #pragma unroll
            for (int g = 0; g < 2; g++) {
                f32x4 scr[4];
                __builtin_amdgcn_s_setprio(1);
                #pragma unroll
                for (int jt = 0; jt < 4; jt++) {
                    f32x4 z = {};
                    s8v b0 = *(const s8v*)&Ks[jt * 16 + qm][quad * 8];
                    s8v b1 = *(const s8v*)&Ks[jt * 16 + qm][32 + quad * 8];
                    z = __builtin_amdgcn_mfma_f32_16x16x32_bf16(qa[g][0], b0, z, 0, 0, 0);
                    z = __builtin_amdgcn_mfma_f32_16x16x32_bf16(qa[g][1], b1, z, 0, 0, 0);
                    scr[jt] = z;
                }
                __builtin_amdgcn_s_setprio(0);
                #pragma unroll
                for (int jt = 0; jt < 4; jt++) {
                    #pragma unroll
                    for (int r = 0; r < 4; r++) {
                        float term = fminf(aqp[g][r] - bk[jt], NEG8L2);
                        float pf = exp2f(fmaf(scr[jt][r], SCL2, term));
                        bf16 pb = __float2bfloat16(pf);
                        l[g][r] += __bfloat162float(pb);
                        Pw[wave][g * 16 + quad * 4 + r][jt * 16 + qm] = pb;
                    }
                }
            }
            __builtin_amdgcn_wave_barrier();
            __builtin_amdgcn_s_setprio(1);
            #pragma unroll
            for (int g = 0; g < 2; g++) {
                s8v pa0 = *(const s8v*)&Pw[wave][g * 16 + qm][quad * 8];
                s8v pa1 = *(const s8v*)&Pw[wave][g * 16 + qm][32 + quad * 8];
                #pragma unroll
                for (int dt = 0; dt < 4; dt++) {
                    s8v vb0 = *(const s8v*)&Vt[dt * 16 + qm][quad * 8];
                    s8v vb1 = *(const s8v*)&Vt[dt * 16 + qm][32 + quad * 8];
                    o[g][dt] = __builtin_amdgcn_mfma_f32_16x16x32_bf16(pa0, vb0, o[g][dt], 0, 0, 0);
                    o[g][dt] = __builtin_amdgcn_mfma_f32_16x16x32_bf16(pa1, vb1, o[g][dt], 0, 0, 0);
                }
            }
            __builtin_amdgcn_s_setprio(0);
            __syncthreads();
        }
    }
    #pragma unroll
    for (int g = 0; g < 2; g++)
        #pragma unroll
        for (int r = 0; r < 4; r++) {
            float s = l[g][r];
            s += __shfl_xor(s, 1); s += __shfl_xor(s, 2);
            s += __shfl_xor(s, 4); s += __shfl_xor(s, 8);
            l[g][r] = 1.0f / s;
        }
    #pragma unroll
    for (int g = 0; g < 2; g++)
        #pragma unroll
        for (int dt = 0; dt < 4; dt++)
            #pragma unroll
            for (int r = 0; r < 4; r++) {
                size_t idx = ((size_t)(b * SEQ + qbase + g * 16 + quad * 4 + r)) * D_MODEL + h * HD + dt * 16 + qm;
                Y[idx] = __float2bfloat16(o[g][dt][r] * l[g][r]);
            }
}

// ---------------- router: gates, top-2 weights, aux, per-expert token lists ----------------
__global__ __launch_bounds__(256) void router_k(
    const float* __restrict__ xf, const float* __restrict__ rw,
    float* __restrict__ wts, float* __restrict__ auxb,
    int* __restrict__ cnt, int* __restrict__ elist)
{
    const int wave = threadIdx.x >> 6, lane = threadIdx.x & 63;
    float4 w[4][4];
    #pragma unroll
    for (int e = 0; e < 4; e++)
        #pragma unroll
        for (int c = 0; c < 4; c++)
            w[e][c] = *(const float4*)&rw[e * D_MODEL + lane * 16 + c * 4];
    float ag[4] = {0.f, 0.f, 0.f, 0.f};
    float ac[4] = {0.f, 0.f, 0.f, 0.f};
    __shared__ int sel[16][2];
    __shared__ float sh[4][8];
    const int t0 = (blockIdx.x * 4 + wave) * 4;
    #pragma unroll
    for (int i = 0; i < 4; i++) {
        const int tk = t0 + i;
        const float* xr = xf + (size_t)tk * D_MODEL + lane * 16;
        float4 xv[4];
        #pragma unroll
        for (int c = 0; c < 4; c++) xv[c] = *(const float4*)&xr[c * 4];
        float p[4] = {0.f, 0.f, 0.f, 0.f};
        #pragma unroll
        for (int e = 0; e < 4; e++)
            #pragma unroll
            for (int c = 0; c < 4; c++) {
                p[e] = fmaf(xv[c].x, w[e][c].x, p[e]);
                p[e] = fmaf(xv[c].y, w[e][c].y, p[e]);
                p[e] = fmaf(xv[c].z, w[e][c].z, p[e]);
                p[e] = fmaf(xv[c].w, w[e][c].w, p[e]);
            }
        #pragma unroll
        for (int o = 1; o < 64; o <<= 1) {
            p[0] += __shfl_xor(p[0], o); p[1] += __shfl_xor(p[1], o);
            p[2] += __shfl_xor(p[2], o); p[3] += __shfl_xor(p[3], o);
        }
        float g[4];
        float mx = fmaxf(fmaxf(p[0], p[1]), fmaxf(p[2], p[3]));
        float se = 0.f;
        #pragma unroll
        for (int e = 0; e < 4; e++) { g[e] = __expf(p[e] - mx); se += g[e]; }
        #pragma unroll
        for (int e = 0; e < 4; e++) g[e] /= se;
        int i1 = 0; float v1 = g[0];
        #pragma unroll
        for (int e = 1; e < 4; e++) if (g[e] > v1) { v1 = g[e]; i1 = e; }
        int i2 = -1; float v2 = -1.f;
        #pragma unroll
        for (int e = 0; e < 4; e++) if (e != i1 && g[e] > v2) { v2 = g[e]; i2 = e; }
        float sw = fmaxf(v1 + v2, 1e-9f);
        if (lane < 4) {
            float wv = (lane == i1) ? v1 / sw : ((lane == i2) ? v2 / sw : 0.f);
            wts[(size_t)tk * 4 + lane] = wv;
        }
        if (lane == 0) {
            #pragma unroll
            for (int e = 0; e < 4; e++) ag[e] += g[e];
            ac[i1] += 1.f; ac[i2] += 1.f;
            sel[wave * 4 + i][0] = i1;
            sel[wave * 4 + i][1] = i2;
        }
    }
    if (lane == 0)
        #pragma unroll
        for (int e = 0; e < 4; e++) { sh[wave][e] = ag[e]; sh[wave][4 + e] = ac[e]; }
    __syncthreads();
    if (threadIdx.x < 8) {
        float s = sh[0][threadIdx.x] + sh[1][threadIdx.x] + sh[2][threadIdx.x] + sh[3][threadIdx.x];
        atomicAdd(&auxb[threadIdx.x], s);
    }
    if (threadIdx.x < 4) {
        const int e = threadIdx.x;
        int loc[16]; int c = 0;
        #pragma unroll
        for (int s = 0; s < 16; s++)
            if (sel[s][0] == e || sel[s][1] == e) loc[c++] = blockIdx.x * 16 + s;
        if (c) {
            int base = atomicAdd(&cnt[e], c);
            for (int k = 0; k < c; k++) elist[e * TOKENS + base + k] = loc[k];
        }
    }
}

// ---------------- final: out = x_s + depthwise-conv5(Tr) + tb ----------------
__global__ __launch_bounds__(256) void final_k(
    const float* __restrict__ xs, const float* __restrict__ Tr,
    const float* __restrict__ tw, const float* __restrict__ tb, float* __restrict__ out)
{
    int n = blockIdx.x, b = blockIdx.y, t = threadIdx.x;
    for (int d = t; d < D_MODEL; d += 256) {
        float acc = tb[d];
        #pragma unroll
        for (int j = 0; j < 5; j++) {
            int i = n + j - 2;
            if (i >= 0 && i < SEQ)
                acc += Tr[((size_t)(b * SEQ + i)) * D_MODEL + d] * tw[d * 5 + j];
        }
        size_t idx = ((size_t)(b * SEQ + n)) * D_MODEL + d;
        out[idx] = xs[idx] + acc;
    }
}

__global__ void aux_k(const float* __restrict__ ab, float* __restrict__ out) {
    if (threadIdx.x == 0 && blockIdx.x == 0) {
        float a = 0.f;
        for (int e = 0; e < 4; e++)
            a += (ab[e] / (float)TOKENS) * (ab[4 + e] / (float)TOKENS);
        out[0] = 4.0f * a;
    }
}

extern "C" void kernel_launch(void* const* d_in, const int* in_sizes, int n_in,
                              void* d_out, int out_size, void* d_ws, size_t ws_size,
                              hipStream_t stream)
{
    const float* x    = (const float*)d_in[0];
    const float* qw   = (const float*)d_in[1];
    const float* qb   = (const float*)d_in[2];
    const float* kw   = (const float*)d_in[3];
    const float* kb   = (const float*)d_in[4];
    const float* vw   = (const float*)d_in[5];
    const float* vb   = (const float*)d_in[6];
    const float* ow   = (const float*)d_in[7];
    const float* ob   = (const float*)d_in[8];
    const float* n1g  = (const float*)d_in[9];
    const float* n1b  = (const float*)d_in[10];
    const float* n2g  = (const float*)d_in[11];
    const float* n2b  = (const float*)d_in[12];
    const float* alpha= (const float*)d_in[13];
    const float* dw7  = (const float*)d_in[14];
    const float* dw25 = (const float*)d_in[15];
    const float* dw49 = (const float*)d_in[16];
    const float* rw   = (const float*)d_in[17];
    const float* ew1  = (const float*)d_in[18];
    const float* eb1  = (const float*)d_in[19];
    const float* ew2  = (const float*)d_in[20];
    const float* eb2  = (const float*)d_in[21];
    const float* tw   = (const float*)d_in[22];
    const float* tb   = (const float*)d_in[23];

    char* ws = (char*)d_ws;
    const size_t MBy = 1ull << 20;
    float* S    = (float*)(ws + 0 * MBy);
    float* Tr   = (float*)(ws + 32 * MBy);
    float* XF   = (float*)(ws + 64 * MBy);
    bf16*  SNB  = (bf16*)(ws + 96 * MBy);
    bf16*  QKVB = (bf16*)(ws + 112 * MBy);   // [8192, 3072] packed Q|K|V (112..160)
    bf16*  XFB  = (bf16*)(ws + 160 * MBy);
    bf16*  WQ   = (bf16*)(ws + 176 * MBy);   // WQ|WK|WV contiguous = fused [3072,1024]
    bf16*  WK   = (bf16*)(ws + 178 * MBy);
    bf16*  WV   = (bf16*)(ws + 180 * MBy);
    bf16*  WO   = (bf16*)(ws + 182 * MBy);
    bf16*  WE1  = (bf16*)(ws + 184 * MBy);
    bf16*  WE2  = (bf16*)(ws + 200 * MBy);
    float* WTS  = (float*)(ws + 216 * MBy);
    float* AUXB = (float*)(ws + 217 * MBy);          // 8 floats
    int*   CNT  = (int*)(AUXB + 8);                  // 4 ints
    float* QKVBIAS = (float*)(ws + 217 * MBy + 4096); // 3072 floats
    int*   ELST = (int*)(ws + 218 * MBy);            // 4 * 8192 ints
    bf16*  YB = SNB;
    bf16*  HB = (bf16*)(ws + 112 * MBy);   // [8192,2048] reuses QKV region (dead after attn)

    f2b_k<<<2048, 256, 0, stream>>>(qw, WQ, D_MODEL * D_MODEL);
    f2b_k<<<2048, 256, 0, stream>>>(kw, WK, D_MODEL * D_MODEL);
    f2b_k<<<2048, 256, 0, stream>>>(vw, WV, D_MODEL * D_MODEL);
    f2b_k<<<2048, 256, 0, stream>>>(ow, WO, D_MODEL * D_MODEL);
    f2b_k<<<4096, 256, 0, stream>>>(ew1, WE1, 4 * MOE_H * D_MODEL);
    f2b_k<<<4096, 256, 0, stream>>>(ew2, WE2, 4 * D_MODEL * MOE_H);
    cat3_k<<<12, 256, 0, stream>>>(qb, kb, vb, QKVBIAS);

    decomp_k<<<dim3(SEQ / TN, D_MODEL / TD, NB), 256, 0, stream>>>(x, alpha, dw7, dw25, dw49, Tr, S);

    ln_k<<<TOKENS, 256, 0, stream>>>(S, n1g, n1b, SNB, nullptr);

    // fused QKV projection: [8192,1024] @ [3072,1024]^T -> [8192,3072]
    gemm_nt<0, 1, 0><<<dim3(64, 24), 256, 0, stream>>>(SNB, WQ, QKVBIAS, nullptr, nullptr, 0, QKVB, TOKENS, D_MODEL, QKV_S, nullptr, nullptr);

    attn_k<<<dim3(SEQ / 128, NHEAD, NB), 256, 0, stream>>>(QKVB, YB);

    gemm_nt<0, 0, 0><<<dim3(64, 8), 256, 0, stream>>>(YB, WO, ob, S, nullptr, 0, S, TOKENS, D_MODEL, D_MODEL, nullptr, nullptr);

    ln_k<<<TOKENS, 256, 0, stream>>>(S, n2g, n2b, XFB, XF);

    hipMemsetAsync(AUXB, 0, 64, stream);
    router_k<<<TOKENS / 16, 256, 0, stream>>>(XF, rw, WTS, AUXB, CNT, ELST);

    // sparse top-2 MoE: only routed tokens, gathered per expert
    for (int e = 0; e < 4; e++) {
        gemm_nt<1, 1, 1><<<dim3(64, 16), 256, 0, stream>>>(
            XFB, WE1 + (size_t)e * MOE_H * D_MODEL, eb1 + e * MOE_H,
            nullptr, nullptr, 0, HB, TOKENS, D_MODEL, MOE_H,
            ELST + e * TOKENS, CNT + e);
        gemm_nt<0, 2, 2><<<dim3(64, 8), 256, 0, stream>>>(
            HB, WE2 + (size_t)e * D_MODEL * MOE_H, eb2 + e * D_MODEL,
            nullptr, WTS + e, 4, S, TOKENS, MOE_H, D_MODEL,
            ELST + e * TOKENS, CNT + e);
    }

    final_k<<<dim3(SEQ, NB), 256, 0, stream>>>(S, Tr, tw, tb, (float*)d_out);
    aux_k<<<1, 64, 0, stream>>>(AUXB, (float*)d_out + (out_size - 1));
}

// Round 4
// 1124.143 us; speedup vs baseline: 1.0637x; 1.0637x over previous
//
#include <hip/hip_runtime.h>
#include <hip/hip_bf16.h>
#include <math.h>

using bf16 = __hip_bfloat16;
typedef __attribute__((ext_vector_type(8))) short s8v;
typedef __attribute__((ext_vector_type(4))) float f32x4;

#define D_MODEL 1024
#define NB 8
#define SEQ 1024
#define NHEAD 16
#define HD 64
#define MOE_H 2048
#define TOKENS (NB*SEQ)
#define QKV_S 3072   // fused QKV row stride

// ---------------- fp32 -> bf16 convert ----------------
__global__ void f2b_k(const float* __restrict__ in, bf16* __restrict__ out, int n) {
    int i = blockIdx.x * blockDim.x + threadIdx.x;
    int stride = gridDim.x * blockDim.x;
    for (; i < n; i += stride) out[i] = __float2bfloat16(in[i]);
}

// concat 3x1024 bias vectors into one 3072 buffer
__global__ void cat3_k(const float* __restrict__ a, const float* __restrict__ b,
                       const float* __restrict__ c, float* __restrict__ o) {
    int i = blockIdx.x * blockDim.x + threadIdx.x;
    if (i < 1024) o[i] = a[i];
    else if (i < 2048) o[i] = b[i - 1024];
    else if (i < 3072) o[i] = c[i - 2048];
}

// prefix sums of the 4 expert counts
__global__ void prefix_k(const int* __restrict__ cnt, int* __restrict__ off) {
    if (threadIdx.x == 0 && blockIdx.x == 0) {
        int s = 0;
        for (int e = 0; e < 4; e++) { off[e] = s; s += cnt[e]; }
    }
}

// ---------------- decomposition: trend + seasonal (LDS-tiled stencil) ----------------
#define TN 128
#define TD 64
__global__ __launch_bounds__(256) void decomp_k(
    const float* __restrict__ x, const float* __restrict__ alpha,
    const float* __restrict__ dw7, const float* __restrict__ dw25,
    const float* __restrict__ dw49, float* __restrict__ Tr, float* __restrict__ S)
{
    __shared__ float xs[TN + 48][TD];
    const int n0 = blockIdx.x * TN, d0 = blockIdx.y * TD, b = blockIdx.z;
    for (int i = threadIdx.x; i < (TN + 48) * (TD / 4); i += 256) {
        int r = i / (TD / 4), c4 = (i % (TD / 4)) * 4;
        int n = n0 + r - 24;
        if (n < 0) n = -n;
        if (n > SEQ - 1) n = 2 * (SEQ - 1) - n;
        *(float4*)&xs[r][c4] =
            *(const float4*)&x[((size_t)(b * SEQ + n)) * D_MODEL + d0 + c4];
    }
    float a0 = alpha[0], a1 = alpha[1], a2 = alpha[2];
    float mx = fmaxf(a0, fmaxf(a1, a2));
    float e0 = __expf(a0 - mx), e1 = __expf(a1 - mx), e2 = __expf(a2 - mx);
    float inv = 1.0f / (e0 + e1 + e2);
    float w7 = e0 * inv, w25 = e1 * inv, w49 = e2 * inv;
    const int dl = threadIdx.x & 63;
    const int nt = threadIdx.x >> 6;
    const int d = d0 + dl;
    float w[49];
    #pragma unroll
    for (int j = 0; j < 49; j++) {
        float v = w49 * dw49[d * 49 + j];
        if (j >= 12 && j < 37) v += w25 * dw25[d * 25 + j - 12];
        if (j >= 21 && j < 28) v += w7 * dw7[d * 7 + j - 21];
        w[j] = v;
    }
    __syncthreads();
    for (int nl = nt; nl < TN; nl += 4) {
        float acc = 0.f;
        #pragma unroll
        for (int j = 0; j < 49; j++) acc = fmaf(xs[nl + j][dl], w[j], acc);
        size_t idx = ((size_t)(b * SEQ + n0 + nl)) * D_MODEL + d;
        Tr[idx] = acc;
        S[idx] = xs[nl + 24][dl] - acc;
    }
}

// ---------------- LayerNorm (fp32 in, bf16 out, optional fp32 out) ----------------
__global__ __launch_bounds__(256) void ln_k(
    const float* __restrict__ x, const float* __restrict__ g, const float* __restrict__ b,
    bf16* __restrict__ ob, float* __restrict__ of)
{
    int row = blockIdx.x, t = threadIdx.x;
    const float* xr = x + (size_t)row * D_MODEL;
    float s = 0.f, s2 = 0.f;
    for (int d = t; d < D_MODEL; d += 256) { float v = xr[d]; s += v; s2 += v * v; }
    #pragma unroll
    for (int o = 32; o > 0; o >>= 1) { s += __shfl_down(s, o); s2 += __shfl_down(s2, o); }
    __shared__ float sh[8];
    int wid = t >> 6, lane = t & 63;
    if (lane == 0) { sh[wid] = s; sh[4 + wid] = s2; }
    __syncthreads();
    if (t == 0) {
        float ts = sh[0] + sh[1] + sh[2] + sh[3];
        float t2 = sh[4] + sh[5] + sh[6] + sh[7];
        float m = ts / D_MODEL;
        float var = t2 / D_MODEL - m * m;
        sh[0] = m; sh[1] = rsqrtf(var + 1e-5f);
    }
    __syncthreads();
    float m = sh[0], rs = sh[1];
    for (int d = t; d < D_MODEL; d += 256) {
        float v = (xr[d] - m) * rs * g[d] + b[d];
        ob[(size_t)row * D_MODEL + d] = __float2bfloat16(v);
        if (of) of[(size_t)row * D_MODEL + d] = v;
    }
}

// ---------------- bf16 MFMA GEMM: C[M,O] = A[M,K] @ B[O,K]^T (+bias)(+act) ----------------
// OMODE 0: fp32 out (+resid), 1: bf16 out (compact at off+row for GMODE1), 2: fp32 atomicAdd scatter
// GMODE 0: dense; 1: gather A rows via row_map, store compact; 2: dense compact A, scatter-atomic store
// GMODE!=0: blockIdx.z = expert; B/bias advanced by e*stride; counts/offsets indexed per expert.
template<int ACT, int OMODE, int GMODE>
__global__ __launch_bounds__(256) void gemm_nt(
    const bf16* __restrict__ A, const bf16* __restrict__ B,
    const float* __restrict__ bias, const float* resid,
    const float* __restrict__ rowscale, int rs_stride,
    void* C, int M, int K, int O,
    const int* __restrict__ row_map, const int* __restrict__ cnt_ptr,
    const int* __restrict__ off_ptr, size_t b_estride, int bias_estride)
{
    const int bm = blockIdx.x, bn = blockIdx.y;
    const int e = (GMODE != 0) ? blockIdx.z : 0;
    int M_act = M;
    int off = 0;
    const int* rmap = row_map;
    if (GMODE != 0) {
        M_act = cnt_ptr[e];
        if (bm * 128 >= M_act) return;
        off = off_ptr[e];
        rmap = row_map + e * TOKENS;
        B += (size_t)e * b_estride;
        if (bias) bias += (size_t)e * bias_estride;
    }
    __shared__ bf16 As[128][72];
    __shared__ bf16 Bs[128][72];
    const int t = threadIdx.x;
    const int lane = t & 63, wid = t >> 6;
    const int wm = wid >> 1, wn = wid & 1;
    f32x4 acc[4][4] = {};
    const int lr = t >> 3;
    const int lc = (t & 7) * 8;
    const size_t abase = (GMODE == 2) ? (size_t)(off + bm * 128) * K : (size_t)(bm * 128) * K;
    const size_t bbase = (size_t)(bn * 128) * K;
    int amap[4];
    if (GMODE == 1) {
        #pragma unroll
        for (int p = 0; p < 4; p++) {
            int gr = bm * 128 + p * 32 + lr;
            amap[p] = rmap[gr < M_act ? gr : M_act - 1];
        }
    }
    for (int k0 = 0; k0 < K; k0 += 64) {
        #pragma unroll
        for (int p = 0; p < 4; p++) {
            int r = p * 32 + lr;
            size_t arow = (GMODE == 1) ? (size_t)amap[p] * K : abase + (size_t)r * K;
            *(s8v*)&As[r][lc] = *(const s8v*)&A[arow + k0 + lc];
            *(s8v*)&Bs[r][lc] = *(const s8v*)&B[bbase + (size_t)r * K + k0 + lc];
        }
        __syncthreads();
        const int fr = lane & 15, fq = (lane >> 4) * 8;
        #pragma unroll
        for (int kk = 0; kk < 64; kk += 32) {
            s8v af[4], bfr[4];
            #pragma unroll
            for (int i = 0; i < 4; i++) {
                af[i]  = *(const s8v*)&As[wm * 64 + i * 16 + fr][kk + fq];
                bfr[i] = *(const s8v*)&Bs[wn * 64 + i * 16 + fr][kk + fq];
            }
            #pragma unroll
            for (int i = 0; i < 4; i++)
                #pragma unroll
                for (int j = 0; j < 4; j++)
                    acc[i][j] = __builtin_amdgcn_mfma_f32_16x16x32_bf16(af[i], bfr[j], acc[i][j], 0, 0, 0);
        }
        __syncthreads();
    }
    const int cr = lane & 15, quad = lane >> 4;
    #pragma unroll
    for (int i = 0; i < 4; i++) {
        #pragma unroll
        for (int r = 0; r < 4; r++) {
            int row = bm * 128 + wm * 64 + i * 16 + quad * 4 + r;
            if (GMODE != 0 && row >= M_act) continue;
            int srow = (GMODE == 2) ? rmap[row] : ((GMODE == 1) ? off + row : row);
            #pragma unroll
            for (int j = 0; j < 4; j++) {
                int col = bn * 128 + wn * 64 + j * 16 + cr;
                float v = acc[i][j][r];
                if (bias) v += bias[col];
                if (ACT == 1) v = 0.5f * v * (1.0f + erff(v * 0.70710678118f));
                size_t idx = (size_t)srow * O + col;
                if (OMODE == 0) {
                    float rv = resid ? resid[idx] : 0.0f;
                    ((float*)C)[idx] = rv + v;
                } else if (OMODE == 1) {
                    ((bf16*)C)[idx] = __float2bfloat16(v);
                } else {
                    atomicAdd(&((float*)C)[idx], rowscale[(size_t)srow * rs_stride + e] * v);
                }
            }
        }
    }
}

// ---------------- MFMA flash attention with ALiBi, fixed-shift softmax ----------------
// block: 256 thr = 4 waves, each wave owns 32 q-rows (128 q-rows/block)
// reads packed QKV [tokens, 3072]; T14 async-stage; log2-domain softmax
__global__ __launch_bounds__(256) void attn_k(
    const bf16* __restrict__ QKV, bf16* __restrict__ Y)
{
    __shared__ bf16 Ks[64][72];
    __shared__ bf16 Vt[64][66];
    __shared__ bf16 Pw[4][32][72];
    const int t = threadIdx.x;
    const int wave = t >> 6, lane = t & 63;
    const int qm = lane & 15, quad = lane >> 4;
    const int b = blockIdx.z, h = blockIdx.y;
    const int qbase = blockIdx.x * 128 + wave * 32;
    const float LOG2E = 1.44269504f;
    const float slope2 = exp2f(-0.5f * (float)(h + 1)) * LOG2E;   // slope * log2(e)
    const float NEG8L2 = -11.54156036f;                            // -8 * log2(e)
    const float SCL2   = 0.18033688f;                              // 0.125 * log2(e)

    s8v qa[2][2];
    #pragma unroll
    for (int g = 0; g < 2; g++) {
        const bf16* qp = QKV + ((size_t)(b * SEQ + qbase + g * 16 + qm)) * QKV_S + h * HD;
        qa[g][0] = *(const s8v*)&qp[quad * 8];
        qa[g][1] = *(const s8v*)&qp[32 + quad * 8];
    }
    float aqp[2][4];
    #pragma unroll
    for (int g = 0; g < 2; g++)
        #pragma unroll
        for (int r = 0; r < 4; r++)
            aqp[g][r] = slope2 * (float)(qbase + g * 16 + quad * 4 + r) + NEG8L2;

    f32x4 o[2][4] = {};
    float l[2][4] = {};

    const int sr = t >> 2;
    const int scc = (t & 3) * 16;
    // base for this lane's K row slice; V is +1024 from K within the packed row
    const bf16* kvb = QKV + (size_t)(b * SEQ) * QKV_S + D_MODEL + h * HD + scc;

    {
        const bf16* p0 = kvb + (size_t)sr * QKV_S;
        s8v k0v = *(const s8v*)&p0[0];
        s8v k1v = *(const s8v*)&p0[8];
        s8v v0  = *(const s8v*)&p0[D_MODEL];
        s8v v1  = *(const s8v*)&p0[D_MODEL + 8];

        for (int k0 = 0; k0 < SEQ; k0 += 64) {
            *(s8v*)&Ks[sr][scc] = k0v;
            *(s8v*)&Ks[sr][scc + 8] = k1v;
            #pragma unroll
            for (int j = 0; j < 8; j++) {
                Vt[scc + j][sr]     = ((const bf16*)&v0)[j];
                Vt[scc + 8 + j][sr] = ((const bf16*)&v1)[j];
            }
            __syncthreads();
            if (k0 + 64 < SEQ) {   // T14: issue next tile's loads; latency hides under compute
                const bf16* np = kvb + (size_t)(k0 + 64 + sr) * QKV_S;
                k0v = *(const s8v*)&np[0];
                k1v = *(const s8v*)&np[8];
                v0  = *(const s8v*)&np[D_MODEL];
                v1  = *(const s8v*)&np[D_MODEL + 8];
            }
            float bk[4];
            #pragma unroll
            for (int jt = 0; jt < 4; jt++) bk[jt] = slope2 * (float)(k0 + jt * 16 + qm);
            #pragma unroll
            for (int g = 0; g < 2; g++) {
                f32x4 scr[4];
                #pragma unroll
                for (int jt = 0; jt < 4; jt++) {
                    f32x4 z = {};
                    s8v b0 = *(const s8v*)&Ks[jt * 16 + qm][quad * 8];
                    s8v b1 = *(const s8v*)&Ks[jt * 16 + qm][32 + quad * 8];
                    z = __builtin_amdgcn_mfma_f32_16x16x32_bf16(qa[g][0], b0, z, 0, 0, 0);
                    z = __builtin_amdgcn_mfma_f32_16x16x32_bf16(qa[g][1], b1, z, 0, 0, 0);
                    scr[jt] = z;
                }
                #pragma unroll
                for (int jt = 0; jt < 4; jt++) {
                    #pragma unroll
                    for (int r = 0; r < 4; r++) {
                        float term = fminf(aqp[g][r] - bk[jt], NEG8L2);
                        float pf = exp2f(fmaf(scr[jt][r], SCL2, term));
                        bf16 pb = __float2bfloat16(pf);
                        l[g][r] += __bfloat162float(pb);
                        Pw[wave][g * 16 + quad * 4 + r][jt * 16 + qm] = pb;
                    }
                }
            }
            __builtin_amdgcn_wave_barrier();
            #pragma unroll
            for (int g = 0; g < 2; g++) {
                s8v pa0 = *(const s8v*)&Pw[wave][g * 16 + qm][quad * 8];
                s8v pa1 = *(const s8v*)&Pw[wave][g * 16 + qm][32 + quad * 8];
                #pragma unroll
                for (int dt = 0; dt < 4; dt++) {
                    s8v vb0 = *(const s8v*)&Vt[dt * 16 + qm][quad * 8];
                    s8v vb1 = *(const s8v*)&Vt[dt * 16 + qm][32 + quad * 8];
                    o[g][dt] = __builtin_amdgcn_mfma_f32_16x16x32_bf16(pa0, vb0, o[g][dt], 0, 0, 0);
                    o[g][dt] = __builtin_amdgcn_mfma_f32_16x16x32_bf16(pa1, vb1, o[g][dt], 0, 0, 0);
                }
            }
            __syncthreads();
        }
    }
    #pragma unroll
    for (int g = 0; g < 2; g++)
        #pragma unroll
        for (int r = 0; r < 4; r++) {
            float s = l[g][r];
            s += __shfl_xor(s, 1); s += __shfl_xor(s, 2);
            s += __shfl_xor(s, 4); s += __shfl_xor(s, 8);
            l[g][r] = 1.0f / s;
        }
    #pragma unroll
    for (int g = 0; g < 2; g++)
        #pragma unroll
        for (int dt = 0; dt < 4; dt++)
            #pragma unroll
            for (int r = 0; r < 4; r++) {
                size_t idx = ((size_t)(b * SEQ + qbase + g * 16 + quad * 4 + r)) * D_MODEL + h * HD + dt * 16 + qm;
                Y[idx] = __float2bfloat16(o[g][dt][r] * l[g][r]);
            }
}

// ---------------- router: gates, top-2 weights, aux, per-expert token lists ----------------
__global__ __launch_bounds__(256) void router_k(
    const float* __restrict__ xf, const float* __restrict__ rw,
    float* __restrict__ wts, float* __restrict__ auxb,
    int* __restrict__ cnt, int* __restrict__ elist)
{
    const int wave = threadIdx.x >> 6, lane = threadIdx.x & 63;
    float4 w[4][4];
    #pragma unroll
    for (int e = 0; e < 4; e++)
        #pragma unroll
        for (int c = 0; c < 4; c++)
            w[e][c] = *(const float4*)&rw[e * D_MODEL + lane * 16 + c * 4];
    float ag[4] = {0.f, 0.f, 0.f, 0.f};
    float ac[4] = {0.f, 0.f, 0.f, 0.f};
    __shared__ int sel[16][2];
    __shared__ float sh[4][8];
    const int t0 = (blockIdx.x * 4 + wave) * 4;
    #pragma unroll
    for (int i = 0; i < 4; i++) {
        const int tk = t0 + i;
        const float* xr = xf + (size_t)tk * D_MODEL + lane * 16;
        float4 xv[4];
        #pragma unroll
        for (int c = 0; c < 4; c++) xv[c] = *(const float4*)&xr[c * 4];
        float p[4] = {0.f, 0.f, 0.f, 0.f};
        #pragma unroll
        for (int e = 0; e < 4; e++)
            #pragma unroll
            for (int c = 0; c < 4; c++) {
                p[e] = fmaf(xv[c].x, w[e][c].x, p[e]);
                p[e] = fmaf(xv[c].y, w[e][c].y, p[e]);
                p[e] = fmaf(xv[c].z, w[e][c].z, p[e]);
                p[e] = fmaf(xv[c].w, w[e][c].w, p[e]);
            }
        #pragma unroll
        for (int o = 1; o < 64; o <<= 1) {
            p[0] += __shfl_xor(p[0], o); p[1] += __shfl_xor(p[1], o);
            p[2] += __shfl_xor(p[2], o); p[3] += __shfl_xor(p[3], o);
        }
        float g[4];
        float mx = fmaxf(fmaxf(p[0], p[1]), fmaxf(p[2], p[3]));
        float se = 0.f;
        #pragma unroll
        for (int e = 0; e < 4; e++) { g[e] = __expf(p[e] - mx); se += g[e]; }
        #pragma unroll
        for (int e = 0; e < 4; e++) g[e] /= se;
        int i1 = 0; float v1 = g[0];
        #pragma unroll
        for (int e = 1; e < 4; e++) if (g[e] > v1) { v1 = g[e]; i1 = e; }
        int i2 = -1; float v2 = -1.f;
        #pragma unroll
        for (int e = 0; e < 4; e++) if (e != i1 && g[e] > v2) { v2 = g[e]; i2 = e; }
        float sw = fmaxf(v1 + v2, 1e-9f);
        if (lane < 4) {
            float wv = (lane == i1) ? v1 / sw : ((lane == i2) ? v2 / sw : 0.f);
            wts[(size_t)tk * 4 + lane] = wv;
        }
        if (lane == 0) {
            #pragma unroll
            for (int e = 0; e < 4; e++) ag[e] += g[e];
            ac[i1] += 1.f; ac[i2] += 1.f;
            sel[wave * 4 + i][0] = i1;
            sel[wave * 4 + i][1] = i2;
        }
    }
    if (lane == 0)
        #pragma unroll
        for (int e = 0; e < 4; e++) { sh[wave][e] = ag[e]; sh[wave][4 + e] = ac[e]; }
    __syncthreads();
    if (threadIdx.x < 8) {
        float s = sh[0][threadIdx.x] + sh[1][threadIdx.x] + sh[2][threadIdx.x] + sh[3][threadIdx.x];
        atomicAdd(&auxb[threadIdx.x], s);
    }
    if (threadIdx.x < 4) {
        const int e = threadIdx.x;
        int loc[16]; int c = 0;
        #pragma unroll
        for (int s = 0; s < 16; s++)
            if (sel[s][0] == e || sel[s][1] == e) loc[c++] = blockIdx.x * 16 + s;
        if (c) {
            int base = atomicAdd(&cnt[e], c);
            for (int k = 0; k < c; k++) elist[e * TOKENS + base + k] = loc[k];
        }
    }
}

// ---------------- final: out = x_s + depthwise-conv5(Tr) + tb ----------------
__global__ __launch_bounds__(256) void final_k(
    const float* __restrict__ xs, const float* __restrict__ Tr,
    const float* __restrict__ tw, const float* __restrict__ tb, float* __restrict__ out)
{
    int n = blockIdx.x, b = blockIdx.y, t = threadIdx.x;
    for (int d = t; d < D_MODEL; d += 256) {
        float acc = tb[d];
        #pragma unroll
        for (int j = 0; j < 5; j++) {
            int i = n + j - 2;
            if (i >= 0 && i < SEQ)
                acc += Tr[((size_t)(b * SEQ + i)) * D_MODEL + d] * tw[d * 5 + j];
        }
        size_t idx = ((size_t)(b * SEQ + n)) * D_MODEL + d;
        out[idx] = xs[idx] + acc;
    }
}

__global__ void aux_k(const float* __restrict__ ab, float* __restrict__ out) {
    if (threadIdx.x == 0 && blockIdx.x == 0) {
        float a = 0.f;
        for (int e = 0; e < 4; e++)
            a += (ab[e] / (float)TOKENS) * (ab[4 + e] / (float)TOKENS);
        out[0] = 4.0f * a;
    }
}

extern "C" void kernel_launch(void* const* d_in, const int* in_sizes, int n_in,
                              void* d_out, int out_size, void* d_ws, size_t ws_size,
                              hipStream_t stream)
{
    const float* x    = (const float*)d_in[0];
    const float* qw   = (const float*)d_in[1];
    const float* qb   = (const float*)d_in[2];
    const float* kw   = (const float*)d_in[3];
    const float* kb   = (const float*)d_in[4];
    const float* vw   = (const float*)d_in[5];
    const float* vb   = (const float*)d_in[6];
    const float* ow   = (const float*)d_in[7];
    const float* ob   = (const float*)d_in[8];
    const float* n1g  = (const float*)d_in[9];
    const float* n1b  = (const float*)d_in[10];
    const float* n2g  = (const float*)d_in[11];
    const float* n2b  = (const float*)d_in[12];
    const float* alpha= (const float*)d_in[13];
    const float* dw7  = (const float*)d_in[14];
    const float* dw25 = (const float*)d_in[15];
    const float* dw49 = (const float*)d_in[16];
    const float* rw   = (const float*)d_in[17];
    const float* ew1  = (const float*)d_in[18];
    const float* eb1  = (const float*)d_in[19];
    const float* ew2  = (const float*)d_in[20];
    const float* eb2  = (const float*)d_in[21];
    const float* tw   = (const float*)d_in[22];
    const float* tb   = (const float*)d_in[23];

    char* ws = (char*)d_ws;
    const size_t MBy = 1ull << 20;
    float* S    = (float*)(ws + 0 * MBy);
    float* Tr   = (float*)(ws + 32 * MBy);
    float* XF   = (float*)(ws + 64 * MBy);
    bf16*  SNB  = (bf16*)(ws + 96 * MBy);    // [8192,1024] bf16; also attn Y
    bf16*  QKVB = (bf16*)(ws + 112 * MBy);   // [8192, 3072] packed Q|K|V (112..160)
    bf16*  XFB  = (bf16*)(ws + 160 * MBy);
    bf16*  WQ   = (bf16*)(ws + 176 * MBy);   // WQ|WK|WV contiguous = fused [3072,1024]
    bf16*  WK   = (bf16*)(ws + 178 * MBy);
    bf16*  WV   = (bf16*)(ws + 180 * MBy);
    bf16*  WO   = (bf16*)(ws + 182 * MBy);
    bf16*  WE1  = (bf16*)(ws + 184 * MBy);
    bf16*  WE2  = (bf16*)(ws + 200 * MBy);
    float* WTS  = (float*)(ws + 216 * MBy);
    float* AUXB = (float*)(ws + 217 * MBy);           // 8 floats
    int*   CNT  = (int*)(AUXB + 8);                   // 4 ints
    int*   OFF  = CNT + 4;                            // 4 ints (prefix sums)
    float* QKVBIAS = (float*)(ws + 217 * MBy + 4096); // 3072 floats
    int*   ELST = (int*)(ws + 218 * MBy);             // 4 * 8192 ints
    bf16*  YB = SNB;
    // compact MoE hidden: 16384 rows x 2048 bf16 = 64 MiB, reuses dead SNB+QKVB (96..160)
    bf16*  HALL = (bf16*)(ws + 96 * MBy);

    f2b_k<<<2048, 256, 0, stream>>>(qw, WQ, D_MODEL * D_MODEL);
    f2b_k<<<2048, 256, 0, stream>>>(kw, WK, D_MODEL * D_MODEL);
    f2b_k<<<2048, 256, 0, stream>>>(vw, WV, D_MODEL * D_MODEL);
    f2b_k<<<2048, 256, 0, stream>>>(ow, WO, D_MODEL * D_MODEL);
    f2b_k<<<4096, 256, 0, stream>>>(ew1, WE1, 4 * MOE_H * D_MODEL);
    f2b_k<<<4096, 256, 0, stream>>>(ew2, WE2, 4 * D_MODEL * MOE_H);
    cat3_k<<<12, 256, 0, stream>>>(qb, kb, vb, QKVBIAS);

    decomp_k<<<dim3(SEQ / TN, D_MODEL / TD, NB), 256, 0, stream>>>(x, alpha, dw7, dw25, dw49, Tr, S);

    ln_k<<<TOKENS, 256, 0, stream>>>(S, n1g, n1b, SNB, nullptr);

    // fused QKV projection: [8192,1024] @ [3072,1024]^T -> [8192,3072]
    gemm_nt<0, 1, 0><<<dim3(64, 24), 256, 0, stream>>>(SNB, WQ, QKVBIAS, nullptr, nullptr, 0, QKVB, TOKENS, D_MODEL, QKV_S, nullptr, nullptr, nullptr, 0, 0);

    attn_k<<<dim3(SEQ / 128, NHEAD, NB), 256, 0, stream>>>(QKVB, YB);

    gemm_nt<0, 0, 0><<<dim3(64, 8), 256, 0, stream>>>(YB, WO, ob, S, nullptr, 0, S, TOKENS, D_MODEL, D_MODEL, nullptr, nullptr, nullptr, 0, 0);

    ln_k<<<TOKENS, 256, 0, stream>>>(S, n2g, n2b, XFB, XF);

    hipMemsetAsync(AUXB, 0, 64, stream);
    router_k<<<TOKENS / 16, 256, 0, stream>>>(XF, rw, WTS, AUXB, CNT, ELST);
    prefix_k<<<1, 64, 0, stream>>>(CNT, OFF);

    // sparse top-2 MoE, all experts batched via blockIdx.z
    // up: XFB gathered -> HALL compact (gelu);   down: HALL -> S (atomic scatter-add)
    gemm_nt<1, 1, 1><<<dim3(64, MOE_H / 128, 4), 256, 0, stream>>>(
        XFB, WE1, eb1, nullptr, nullptr, 0, HALL, TOKENS, D_MODEL, MOE_H,
        ELST, CNT, OFF, (size_t)MOE_H * D_MODEL, MOE_H);
    gemm_nt<0, 2, 2><<<dim3(64, D_MODEL / 128, 4), 256, 0, stream>>>(
        HALL, WE2, eb2, nullptr, WTS, 4, S, TOKENS, MOE_H, D_MODEL,
        ELST, CNT, OFF, (size_t)D_MODEL * MOE_H, D_MODEL);

    final_k<<<dim3(SEQ, NB), 256, 0, stream>>>(S, Tr, tw, tb, (float*)d_out);
    aux_k<<<1, 64, 0, stream>>>(AUXB, (float*)d_out + (out_size - 1));
}

// Round 5
// 987.470 us; speedup vs baseline: 1.2109x; 1.1384x over previous
//
#include <hip/hip_runtime.h>
#include <hip/hip_bf16.h>
#include <math.h>

using bf16 = __hip_bfloat16;
typedef __attribute__((ext_vector_type(8))) short s8v;
typedef __attribute__((ext_vector_type(4))) float f32x4;

#define D_MODEL 1024
#define NB 8
#define SEQ 1024
#define NHEAD 16
#define HD 64
#define MOE_H 2048
#define TOKENS (NB*SEQ)
#define QKV_S 3072   // fused QKV row stride

// ---------------- fp32 -> bf16 convert ----------------
__global__ void f2b_k(const float* __restrict__ in, bf16* __restrict__ out, int n) {
    int i = blockIdx.x * blockDim.x + threadIdx.x;
    int stride = gridDim.x * blockDim.x;
    for (; i < n; i += stride) out[i] = __float2bfloat16(in[i]);
}

// concat 3x1024 bias vectors into one 3072 buffer
__global__ void cat3_k(const float* __restrict__ a, const float* __restrict__ b,
                       const float* __restrict__ c, float* __restrict__ o) {
    int i = blockIdx.x * blockDim.x + threadIdx.x;
    if (i < 1024) o[i] = a[i];
    else if (i < 2048) o[i] = b[i - 1024];
    else if (i < 3072) o[i] = c[i - 2048];
}

// prefix sums of the 4 expert counts
__global__ void prefix_k(const int* __restrict__ cnt, int* __restrict__ off) {
    if (threadIdx.x == 0 && blockIdx.x == 0) {
        int s = 0;
        for (int e = 0; e < 4; e++) { off[e] = s; s += cnt[e]; }
    }
}

// ---------------- decomposition: trend + seasonal (LDS-tiled stencil) ----------------
#define TN 128
#define TD 64
__global__ __launch_bounds__(256) void decomp_k(
    const float* __restrict__ x, const float* __restrict__ alpha,
    const float* __restrict__ dw7, const float* __restrict__ dw25,
    const float* __restrict__ dw49, float* __restrict__ Tr, float* __restrict__ S)
{
    __shared__ float xs[TN + 48][TD];
    const int n0 = blockIdx.x * TN, d0 = blockIdx.y * TD, b = blockIdx.z;
    for (int i = threadIdx.x; i < (TN + 48) * (TD / 4); i += 256) {
        int r = i / (TD / 4), c4 = (i % (TD / 4)) * 4;
        int n = n0 + r - 24;
        if (n < 0) n = -n;
        if (n > SEQ - 1) n = 2 * (SEQ - 1) - n;
        *(float4*)&xs[r][c4] =
            *(const float4*)&x[((size_t)(b * SEQ + n)) * D_MODEL + d0 + c4];
    }
    float a0 = alpha[0], a1 = alpha[1], a2 = alpha[2];
    float mx = fmaxf(a0, fmaxf(a1, a2));
    float e0 = __expf(a0 - mx), e1 = __expf(a1 - mx), e2 = __expf(a2 - mx);
    float inv = 1.0f / (e0 + e1 + e2);
    float w7 = e0 * inv, w25 = e1 * inv, w49 = e2 * inv;
    const int dl = threadIdx.x & 63;
    const int nt = threadIdx.x >> 6;
    const int d = d0 + dl;
    float w[49];
    #pragma unroll
    for (int j = 0; j < 49; j++) {
        float v = w49 * dw49[d * 49 + j];
        if (j >= 12 && j < 37) v += w25 * dw25[d * 25 + j - 12];
        if (j >= 21 && j < 28) v += w7 * dw7[d * 7 + j - 21];
        w[j] = v;
    }
    __syncthreads();
    for (int nl = nt; nl < TN; nl += 4) {
        float acc = 0.f;
        #pragma unroll
        for (int j = 0; j < 49; j++) acc = fmaf(xs[nl + j][dl], w[j], acc);
        size_t idx = ((size_t)(b * SEQ + n0 + nl)) * D_MODEL + d;
        Tr[idx] = acc;
        S[idx] = xs[nl + 24][dl] - acc;
    }
}

// ---------------- LayerNorm (fp32 in, bf16 out, optional fp32 out) ----------------
__global__ __launch_bounds__(256) void ln_k(
    const float* __restrict__ x, const float* __restrict__ g, const float* __restrict__ b,
    bf16* __restrict__ ob, float* __restrict__ of)
{
    int row = blockIdx.x, t = threadIdx.x;
    const float* xr = x + (size_t)row * D_MODEL;
    float s = 0.f, s2 = 0.f;
    for (int d = t; d < D_MODEL; d += 256) { float v = xr[d]; s += v; s2 += v * v; }
    #pragma unroll
    for (int o = 32; o > 0; o >>= 1) { s += __shfl_down(s, o); s2 += __shfl_down(s2, o); }
    __shared__ float sh[8];
    int wid = t >> 6, lane = t & 63;
    if (lane == 0) { sh[wid] = s; sh[4 + wid] = s2; }
    __syncthreads();
    if (t == 0) {
        float ts = sh[0] + sh[1] + sh[2] + sh[3];
        float t2 = sh[4] + sh[5] + sh[6] + sh[7];
        float m = ts / D_MODEL;
        float var = t2 / D_MODEL - m * m;
        sh[0] = m; sh[1] = rsqrtf(var + 1e-5f);
    }
    __syncthreads();
    float m = sh[0], rs = sh[1];
    for (int d = t; d < D_MODEL; d += 256) {
        float v = (xr[d] - m) * rs * g[d] + b[d];
        ob[(size_t)row * D_MODEL + d] = __float2bfloat16(v);
        if (of) of[(size_t)row * D_MODEL + d] = v;
    }
}

// ---------------- bf16 MFMA GEMM: C[M,O] = A[M,K] @ B[O,K]^T (+bias)(+act) ----------------
// OMODE 0: fp32 out (+resid), 1: bf16 out (compact at off+row for GMODE1), 2: fp32 atomicAdd scatter
// GMODE 0: dense; 1: gather A rows via row_map, store compact; 2: dense compact A, scatter-atomic store
// GMODE!=0: blockIdx.z = expert; B/bias advanced by e*stride; counts/offsets indexed per expert.
// T14 pipeline: loop-carried reg staging; next tile's global loads issued during compute.
template<int ACT, int OMODE, int GMODE>
__global__ __launch_bounds__(256) void gemm_nt(
    const bf16* __restrict__ A, const bf16* __restrict__ B,
    const float* __restrict__ bias, const float* resid,
    const float* __restrict__ rowscale, int rs_stride,
    void* C, int M, int K, int O,
    const int* __restrict__ row_map, const int* __restrict__ cnt_ptr,
    const int* __restrict__ off_ptr, size_t b_estride, int bias_estride)
{
    const int bm = blockIdx.x, bn = blockIdx.y;
    const int e = (GMODE != 0) ? blockIdx.z : 0;
    int M_act = M;
    int off = 0;
    const int* rmap = row_map;
    if (GMODE != 0) {
        M_act = cnt_ptr[e];
        if (bm * 128 >= M_act) return;
        off = off_ptr[e];
        rmap = row_map + e * TOKENS;
        B += (size_t)e * b_estride;
        if (bias) bias += (size_t)e * bias_estride;
    }
    __shared__ bf16 As[128][72];
    __shared__ bf16 Bs[128][72];
    const int t = threadIdx.x;
    const int lane = t & 63, wid = t >> 6;
    const int wm = wid >> 1, wn = wid & 1;
    f32x4 acc[4][4] = {};
    const int lr = t >> 3;
    const int lc = (t & 7) * 8;
    const size_t abase = (GMODE == 2) ? (size_t)(off + bm * 128) * K : (size_t)(bm * 128) * K;
    const size_t bbase = (size_t)(bn * 128) * K;
    size_t arow[4];
    #pragma unroll
    for (int p = 0; p < 4; p++) {
        int r = p * 32 + lr;
        if (GMODE == 1) {
            int gr = bm * 128 + r;
            arow[p] = (size_t)rmap[gr < M_act ? gr : M_act - 1] * K;
        } else {
            arow[p] = abase + (size_t)r * K;
        }
    }
    // prologue: load tile 0 into regs
    s8v ra[4], rb[4];
    #pragma unroll
    for (int p = 0; p < 4; p++) {
        ra[p] = *(const s8v*)&A[arow[p] + lc];
        rb[p] = *(const s8v*)&B[bbase + (size_t)(p * 32 + lr) * K + lc];
    }
    for (int k0 = 0; k0 < K; k0 += 64) {
        // write staged regs to LDS
        #pragma unroll
        for (int p = 0; p < 4; p++) {
            int r = p * 32 + lr;
            *(s8v*)&As[r][lc] = ra[p];
            *(s8v*)&Bs[r][lc] = rb[p];
        }
        __syncthreads();
        // issue next tile's loads; latency hides under the MFMA block below
        if (k0 + 64 < K) {
            const int kn = k0 + 64 + lc;
            #pragma unroll
            for (int p = 0; p < 4; p++) {
                ra[p] = *(const s8v*)&A[arow[p] + kn];
                rb[p] = *(const s8v*)&B[bbase + (size_t)(p * 32 + lr) * K + kn];
            }
        }
        const int fr = lane & 15, fq = (lane >> 4) * 8;
        #pragma unroll
        for (int kk = 0; kk < 64; kk += 32) {
            s8v af[4], bfr[4];
            #pragma unroll
            for (int i = 0; i < 4; i++) {
                af[i]  = *(const s8v*)&As[wm * 64 + i * 16 + fr][kk + fq];
                bfr[i] = *(const s8v*)&Bs[wn * 64 + i * 16 + fr][kk + fq];
            }
            #pragma unroll
            for (int i = 0; i < 4; i++)
                #pragma unroll
                for (int j = 0; j < 4; j++)
                    acc[i][j] = __builtin_amdgcn_mfma_f32_16x16x32_bf16(af[i], bfr[j], acc[i][j], 0, 0, 0);
        }
        __syncthreads();
    }
    const int cr = lane & 15, quad = lane >> 4;
    #pragma unroll
    for (int i = 0; i < 4; i++) {
        #pragma unroll
        for (int r = 0; r < 4; r++) {
            int row = bm * 128 + wm * 64 + i * 16 + quad * 4 + r;
            if (GMODE != 0 && row >= M_act) continue;
            int srow = (GMODE == 2) ? rmap[row] : ((GMODE == 1) ? off + row : row);
            #pragma unroll
            for (int j = 0; j < 4; j++) {
                int col = bn * 128 + wn * 64 + j * 16 + cr;
                float v = acc[i][j][r];
                if (bias) v += bias[col];
                if (ACT == 1) v = 0.5f * v * (1.0f + erff(v * 0.70710678118f));
                size_t idx = (size_t)srow * O + col;
                if (OMODE == 0) {
                    float rv = resid ? resid[idx] : 0.0f;
                    ((float*)C)[idx] = rv + v;
                } else if (OMODE == 1) {
                    ((bf16*)C)[idx] = __float2bfloat16(v);
                } else {
                    atomicAdd(&((float*)C)[idx], rowscale[(size_t)srow * rs_stride + e] * v);
                }
            }
        }
    }
}

// ---------------- MFMA flash attention with ALiBi, fixed-shift softmax ----------------
// block: 256 thr = 4 waves, each wave owns 32 q-rows (128 q-rows/block)
// reads packed QKV [tokens, 3072]; T14 async-stage; log2-domain softmax
__global__ __launch_bounds__(256) void attn_k(
    const bf16* __restrict__ QKV, bf16* __restrict__ Y)
{
    __shared__ bf16 Ks[64][72];
    __shared__ bf16 Vt[64][66];
    __shared__ bf16 Pw[4][32][72];
    const int t = threadIdx.x;
    const int wave = t >> 6, lane = t & 63;
    const int qm = lane & 15, quad = lane >> 4;
    const int b = blockIdx.z, h = blockIdx.y;
    const int qbase = blockIdx.x * 128 + wave * 32;
    const float LOG2E = 1.44269504f;
    const float slope2 = exp2f(-0.5f * (float)(h + 1)) * LOG2E;   // slope * log2(e)
    const float NEG8L2 = -11.54156036f;                            // -8 * log2(e)
    const float SCL2   = 0.18033688f;                              // 0.125 * log2(e)

    s8v qa[2][2];
    #pragma unroll
    for (int g = 0; g < 2; g++) {
        const bf16* qp = QKV + ((size_t)(b * SEQ + qbase + g * 16 + qm)) * QKV_S + h * HD;
        qa[g][0] = *(const s8v*)&qp[quad * 8];
        qa[g][1] = *(const s8v*)&qp[32 + quad * 8];
    }
    float aqp[2][4];
    #pragma unroll
    for (int g = 0; g < 2; g++)
        #pragma unroll
        for (int r = 0; r < 4; r++)
            aqp[g][r] = slope2 * (float)(qbase + g * 16 + quad * 4 + r) + NEG8L2;

    f32x4 o[2][4] = {};
    float l[2][4] = {};

    const int sr = t >> 2;
    const int scc = (t & 3) * 16;
    // base for this lane's K row slice; V is +1024 from K within the packed row
    const bf16* kvb = QKV + (size_t)(b * SEQ) * QKV_S + D_MODEL + h * HD + scc;

    {
        const bf16* p0 = kvb + (size_t)sr * QKV_S;
        s8v k0v = *(const s8v*)&p0[0];
        s8v k1v = *(const s8v*)&p0[8];
        s8v v0  = *(const s8v*)&p0[D_MODEL];
        s8v v1  = *(const s8v*)&p0[D_MODEL + 8];

        for (int k0 = 0; k0 < SEQ; k0 += 64) {
            *(s8v*)&Ks[sr][scc] = k0v;
            *(s8v*)&Ks[sr][scc + 8] = k1v;
            #pragma unroll
            for (int j = 0; j < 8; j++) {
                Vt[scc + j][sr]     = ((const bf16*)&v0)[j];
                Vt[scc + 8 + j][sr] = ((const bf16*)&v1)[j];
            }
            __syncthreads();
            if (k0 + 64 < SEQ) {   // T14: issue next tile's loads; latency hides under compute
                const bf16* np = kvb + (size_t)(k0 + 64 + sr) * QKV_S;
                k0v = *(const s8v*)&np[0];
                k1v = *(const s8v*)&np[8];
                v0  = *(const s8v*)&np[D_MODEL];
                v1  = *(const s8v*)&np[D_MODEL + 8];
            }
            float bk[4];
            #pragma unroll
            for (int jt = 0; jt < 4; jt++) bk[jt] = slope2 * (float)(k0 + jt * 16 + qm);
            #pragma unroll
            for (int g = 0; g < 2; g++) {
                f32x4 scr[4];
                #pragma unroll
                for (int jt = 0; jt < 4; jt++) {
                    f32x4 z = {};
                    s8v b0 = *(const s8v*)&Ks[jt * 16 + qm][quad * 8];
                    s8v b1 = *(const s8v*)&Ks[jt * 16 + qm][32 + quad * 8];
                    z = __builtin_amdgcn_mfma_f32_16x16x32_bf16(qa[g][0], b0, z, 0, 0, 0);
                    z = __builtin_amdgcn_mfma_f32_16x16x32_bf16(qa[g][1], b1, z, 0, 0, 0);
                    scr[jt] = z;
                }
                #pragma unroll
                for (int jt = 0; jt < 4; jt++) {
                    #pragma unroll
                    for (int r = 0; r < 4; r++) {
                        float term = fminf(aqp[g][r] - bk[jt], NEG8L2);
                        float pf = exp2f(fmaf(scr[jt][r], SCL2, term));
                        bf16 pb = __float2bfloat16(pf);
                        l[g][r] += __bfloat162float(pb);
                        Pw[wave][g * 16 + quad * 4 + r][jt * 16 + qm] = pb;
                    }
                }
            }
            __builtin_amdgcn_wave_barrier();
            #pragma unroll
            for (int g = 0; g < 2; g++) {
                s8v pa0 = *(const s8v*)&Pw[wave][g * 16 + qm][quad * 8];
                s8v pa1 = *(const s8v*)&Pw[wave][g * 16 + qm][32 + quad * 8];
                #pragma unroll
                for (int dt = 0; dt < 4; dt++) {
                    s8v vb0 = *(const s8v*)&Vt[dt * 16 + qm][quad * 8];
                    s8v vb1 = *(const s8v*)&Vt[dt * 16 + qm][32 + quad * 8];
                    o[g][dt] = __builtin_amdgcn_mfma_f32_16x16x32_bf16(pa0, vb0, o[g][dt], 0, 0, 0);
                    o[g][dt] = __builtin_amdgcn_mfma_f32_16x16x32_bf16(pa1, vb1, o[g][dt], 0, 0, 0);
                }
            }
            __syncthreads();
        }
    }
    #pragma unroll
    for (int g = 0; g < 2; g++)
        #pragma unroll
        for (int r = 0; r < 4; r++) {
            float s = l[g][r];
            s += __shfl_xor(s, 1); s += __shfl_xor(s, 2);
            s += __shfl_xor(s, 4); s += __shfl_xor(s, 8);
            l[g][r] = 1.0f / s;
        }
    #pragma unroll
    for (int g = 0; g < 2; g++)
        #pragma unroll
        for (int dt = 0; dt < 4; dt++)
            #pragma unroll
            for (int r = 0; r < 4; r++) {
                size_t idx = ((size_t)(b * SEQ + qbase + g * 16 + quad * 4 + r)) * D_MODEL + h * HD + dt * 16 + qm;
                Y[idx] = __float2bfloat16(o[g][dt][r] * l[g][r]);
            }
}

// ---------------- router: gates, top-2 weights, aux, per-expert token lists ----------------
__global__ __launch_bounds__(256) void router_k(
    const float* __restrict__ xf, const float* __restrict__ rw,
    float* __restrict__ wts, float* __restrict__ auxb,
    int* __restrict__ cnt, int* __restrict__ elist)
{
    const int wave = threadIdx.x >> 6, lane = threadIdx.x & 63;
    float4 w[4][4];
    #pragma unroll
    for (int e = 0; e < 4; e++)
        #pragma unroll
        for (int c = 0; c < 4; c++)
            w[e][c] = *(const float4*)&rw[e * D_MODEL + lane * 16 + c * 4];
    float ag[4] = {0.f, 0.f, 0.f, 0.f};
    float ac[4] = {0.f, 0.f, 0.f, 0.f};
    __shared__ int sel[16][2];
    __shared__ float sh[4][8];
    const int t0 = (blockIdx.x * 4 + wave) * 4;
    #pragma unroll
    for (int i = 0; i < 4; i++) {
        const int tk = t0 + i;
        const float* xr = xf + (size_t)tk * D_MODEL + lane * 16;
        float4 xv[4];
        #pragma unroll
        for (int c = 0; c < 4; c++) xv[c] = *(const float4*)&xr[c * 4];
        float p[4] = {0.f, 0.f, 0.f, 0.f};
        #pragma unroll
        for (int e = 0; e < 4; e++)
            #pragma unroll
            for (int c = 0; c < 4; c++) {
                p[e] = fmaf(xv[c].x, w[e][c].x, p[e]);
                p[e] = fmaf(xv[c].y, w[e][c].y, p[e]);
                p[e] = fmaf(xv[c].z, w[e][c].z, p[e]);
                p[e] = fmaf(xv[c].w, w[e][c].w, p[e]);
            }
        #pragma unroll
        for (int o = 1; o < 64; o <<= 1) {
            p[0] += __shfl_xor(p[0], o); p[1] += __shfl_xor(p[1], o);
            p[2] += __shfl_xor(p[2], o); p[3] += __shfl_xor(p[3], o);
        }
        float g[4];
        float mx = fmaxf(fmaxf(p[0], p[1]), fmaxf(p[2], p[3]));
        float se = 0.f;
        #pragma unroll
        for (int e = 0; e < 4; e++) { g[e] = __expf(p[e] - mx); se += g[e]; }
        #pragma unroll
        for (int e = 0; e < 4; e++) g[e] /= se;
        int i1 = 0; float v1 = g[0];
        #pragma unroll
        for (int e = 1; e < 4; e++) if (g[e] > v1) { v1 = g[e]; i1 = e; }
        int i2 = -1; float v2 = -1.f;
        #pragma unroll
        for (int e = 0; e < 4; e++) if (e != i1 && g[e] > v2) { v2 = g[e]; i2 = e; }
        float sw = fmaxf(v1 + v2, 1e-9f);
        if (lane < 4) {
            float wv = (lane == i1) ? v1 / sw : ((lane == i2) ? v2 / sw : 0.f);
            wts[(size_t)tk * 4 + lane] = wv;
        }
        if (lane == 0) {
            #pragma unroll
            for (int e = 0; e < 4; e++) ag[e] += g[e];
            ac[i1] += 1.f; ac[i2] += 1.f;
            sel[wave * 4 + i][0] = i1;
            sel[wave * 4 + i][1] = i2;
        }
    }
    if (lane == 0)
        #pragma unroll
        for (int e = 0; e < 4; e++) { sh[wave][e] = ag[e]; sh[wave][4 + e] = ac[e]; }
    __syncthreads();
    if (threadIdx.x < 8) {
        float s = sh[0][threadIdx.x] + sh[1][threadIdx.x] + sh[2][threadIdx.x] + sh[3][threadIdx.x];
        atomicAdd(&auxb[threadIdx.x], s);
    }
    if (threadIdx.x < 4) {
        const int e = threadIdx.x;
        int loc[16]; int c = 0;
        #pragma unroll
        for (int s = 0; s < 16; s++)
            if (sel[s][0] == e || sel[s][1] == e) loc[c++] = blockIdx.x * 16 + s;
        if (c) {
            int base = atomicAdd(&cnt[e], c);
            for (int k = 0; k < c; k++) elist[e * TOKENS + base + k] = loc[k];
        }
    }
}

// ---------------- final: out = x_s + depthwise-conv5(Tr) + tb ----------------
__global__ __launch_bounds__(256) void final_k(
    const float* __restrict__ xs, const float* __restrict__ Tr,
    const float* __restrict__ tw, const float* __restrict__ tb, float* __restrict__ out)
{
    int n = blockIdx.x, b = blockIdx.y, t = threadIdx.x;
    for (int d = t; d < D_MODEL; d += 256) {
        float acc = tb[d];
        #pragma unroll
        for (int j = 0; j < 5; j++) {
            int i = n + j - 2;
            if (i >= 0 && i < SEQ)
                acc += Tr[((size_t)(b * SEQ + i)) * D_MODEL + d] * tw[d * 5 + j];
        }
        size_t idx = ((size_t)(b * SEQ + n)) * D_MODEL + d;
        out[idx] = xs[idx] + acc;
    }
}

__global__ void aux_k(const float* __restrict__ ab, float* __restrict__ out) {
    if (threadIdx.x == 0 && blockIdx.x == 0) {
        float a = 0.f;
        for (int e = 0; e < 4; e++)
            a += (ab[e] / (float)TOKENS) * (ab[4 + e] / (float)TOKENS);
        out[0] = 4.0f * a;
    }
}

extern "C" void kernel_launch(void* const* d_in, const int* in_sizes, int n_in,
                              void* d_out, int out_size, void* d_ws, size_t ws_size,
                              hipStream_t stream)
{
    const float* x    = (const float*)d_in[0];
    const float* qw   = (const float*)d_in[1];
    const float* qb   = (const float*)d_in[2];
    const float* kw   = (const float*)d_in[3];
    const float* kb   = (const float*)d_in[4];
    const float* vw   = (const float*)d_in[5];
    const float* vb   = (const float*)d_in[6];
    const float* ow   = (const float*)d_in[7];
    const float* ob   = (const float*)d_in[8];
    const float* n1g  = (const float*)d_in[9];
    const float* n1b  = (const float*)d_in[10];
    const float* n2g  = (const float*)d_in[11];
    const float* n2b  = (const float*)d_in[12];
    const float* alpha= (const float*)d_in[13];
    const float* dw7  = (const float*)d_in[14];
    const float* dw25 = (const float*)d_in[15];
    const float* dw49 = (const float*)d_in[16];
    const float* rw   = (const float*)d_in[17];
    const float* ew1  = (const float*)d_in[18];
    const float* eb1  = (const float*)d_in[19];
    const float* ew2  = (const float*)d_in[20];
    const float* eb2  = (const float*)d_in[21];
    const float* tw   = (const float*)d_in[22];
    const float* tb   = (const float*)d_in[23];

    char* ws = (char*)d_ws;
    const size_t MBy = 1ull << 20;
    float* S    = (float*)(ws + 0 * MBy);
    float* Tr   = (float*)(ws + 32 * MBy);
    float* XF   = (float*)(ws + 64 * MBy);
    bf16*  SNB  = (bf16*)(ws + 96 * MBy);    // [8192,1024] bf16; also attn Y
    bf16*  QKVB = (bf16*)(ws + 112 * MBy);   // [8192, 3072] packed Q|K|V (112..160)
    bf16*  XFB  = (bf16*)(ws + 160 * MBy);
    bf16*  WQ   = (bf16*)(ws + 176 * MBy);   // WQ|WK|WV contiguous = fused [3072,1024]
    bf16*  WK   = (bf16*)(ws + 178 * MBy);
    bf16*  WV   = (bf16*)(ws + 180 * MBy);
    bf16*  WO   = (bf16*)(ws + 182 * MBy);
    bf16*  WE1  = (bf16*)(ws + 184 * MBy);
    bf16*  WE2  = (bf16*)(ws + 200 * MBy);
    float* WTS  = (float*)(ws + 216 * MBy);
    float* AUXB = (float*)(ws + 217 * MBy);           // 8 floats
    int*   CNT  = (int*)(AUXB + 8);                   // 4 ints
    int*   OFF  = CNT + 4;                            // 4 ints (prefix sums)
    float* QKVBIAS = (float*)(ws + 217 * MBy + 4096); // 3072 floats
    int*   ELST = (int*)(ws + 218 * MBy);             // 4 * 8192 ints
    bf16*  YB = SNB;
    // compact MoE hidden: 16384 rows x 2048 bf16 = 64 MiB, reuses dead SNB+QKVB (96..160)
    bf16*  HALL = (bf16*)(ws + 96 * MBy);

    f2b_k<<<2048, 256, 0, stream>>>(qw, WQ, D_MODEL * D_MODEL);
    f2b_k<<<2048, 256, 0, stream>>>(kw, WK, D_MODEL * D_MODEL);
    f2b_k<<<2048, 256, 0, stream>>>(vw, WV, D_MODEL * D_MODEL);
    f2b_k<<<2048, 256, 0, stream>>>(ow, WO, D_MODEL * D_MODEL);
    f2b_k<<<4096, 256, 0, stream>>>(ew1, WE1, 4 * MOE_H * D_MODEL);
    f2b_k<<<4096, 256, 0, stream>>>(ew2, WE2, 4 * D_MODEL * MOE_H);
    cat3_k<<<12, 256, 0, stream>>>(qb, kb, vb, QKVBIAS);

    decomp_k<<<dim3(SEQ / TN, D_MODEL / TD, NB), 256, 0, stream>>>(x, alpha, dw7, dw25, dw49, Tr, S);

    ln_k<<<TOKENS, 256, 0, stream>>>(S, n1g, n1b, SNB, nullptr);

    // fused QKV projection: [8192,1024] @ [3072,1024]^T -> [8192,3072]
    gemm_nt<0, 1, 0><<<dim3(64, 24), 256, 0, stream>>>(SNB, WQ, QKVBIAS, nullptr, nullptr, 0, QKVB, TOKENS, D_MODEL, QKV_S, nullptr, nullptr, nullptr, 0, 0);

    attn_k<<<dim3(SEQ / 128, NHEAD, NB), 256, 0, stream>>>(QKVB, YB);

    gemm_nt<0, 0, 0><<<dim3(64, 8), 256, 0, stream>>>(YB, WO, ob, S, nullptr, 0, S, TOKENS, D_MODEL, D_MODEL, nullptr, nullptr, nullptr, 0, 0);

    ln_k<<<TOKENS, 256, 0, stream>>>(S, n2g, n2b, XFB, XF);

    hipMemsetAsync(AUXB, 0, 64, stream);
    router_k<<<TOKENS / 16, 256, 0, stream>>>(XF, rw, WTS, AUXB, CNT, ELST);
    prefix_k<<<1, 64, 0, stream>>>(CNT, OFF);

    // sparse top-2 MoE, all experts batched via blockIdx.z
    // up: XFB gathered -> HALL compact (gelu);   down: HALL -> S (atomic scatter-add)
    gemm_nt<1, 1, 1><<<dim3(64, MOE_H / 128, 4), 256, 0, stream>>>(
        XFB, WE1, eb1, nullptr, nullptr, 0, HALL, TOKENS, D_MODEL, MOE_H,
        ELST, CNT, OFF, (size_t)MOE_H * D_MODEL, MOE_H);
    gemm_nt<0, 2, 2><<<dim3(64, D_MODEL / 128, 4), 256, 0, stream>>>(
        HALL, WE2, eb2, nullptr, WTS, 4, S, TOKENS, MOE_H, D_MODEL,
        ELST, CNT, OFF, (size_t)D_MODEL * MOE_H, D_MODEL);

    final_k<<<dim3(SEQ, NB), 256, 0, stream>>>(S, Tr, tw, tb, (float*)d_out);
    aux_k<<<1, 64, 0, stream>>>(AUXB, (float*)d_out + (out_size - 1));
}

// Round 6
// 889.513 us; speedup vs baseline: 1.3443x; 1.1101x over previous
//
#include <hip/hip_runtime.h>
#include <hip/hip_bf16.h>
#include <math.h>

using bf16 = __hip_bfloat16;
typedef __attribute__((ext_vector_type(8))) short s8v;
typedef __attribute__((ext_vector_type(4))) float f32x4;

#define D_MODEL 1024
#define NB 8
#define SEQ 1024
#define NHEAD 16
#define HD 64
#define MOE_H 2048
#define TOKENS (NB*SEQ)
#define QKV_S 3072   // fused QKV row stride

// ---------------- fp32 -> bf16 convert ----------------
__global__ void f2b_k(const float* __restrict__ in, bf16* __restrict__ out, int n) {
    int i = blockIdx.x * blockDim.x + threadIdx.x;
    int stride = gridDim.x * blockDim.x;
    for (; i < n; i += stride) out[i] = __float2bfloat16(in[i]);
}

// concat 3x1024 bias vectors into one 3072 buffer
__global__ void cat3_k(const float* __restrict__ a, const float* __restrict__ b,
                       const float* __restrict__ c, float* __restrict__ o) {
    int i = blockIdx.x * blockDim.x + threadIdx.x;
    if (i < 1024) o[i] = a[i];
    else if (i < 2048) o[i] = b[i - 1024];
    else if (i < 3072) o[i] = c[i - 2048];
}

// prefix sums of the 4 expert counts
__global__ void prefix_k(const int* __restrict__ cnt, int* __restrict__ off) {
    if (threadIdx.x == 0 && blockIdx.x == 0) {
        int s = 0;
        for (int e = 0; e < 4; e++) { off[e] = s; s += cnt[e]; }
    }
}

// ---------------- decomposition: trend + seasonal (LDS-tiled stencil) ----------------
#define TN 128
#define TD 64
__global__ __launch_bounds__(256) void decomp_k(
    const float* __restrict__ x, const float* __restrict__ alpha,
    const float* __restrict__ dw7, const float* __restrict__ dw25,
    const float* __restrict__ dw49, float* __restrict__ Tr, float* __restrict__ S)
{
    __shared__ float xs[TN + 48][TD];
    const int n0 = blockIdx.x * TN, d0 = blockIdx.y * TD, b = blockIdx.z;
    for (int i = threadIdx.x; i < (TN + 48) * (TD / 4); i += 256) {
        int r = i / (TD / 4), c4 = (i % (TD / 4)) * 4;
        int n = n0 + r - 24;
        if (n < 0) n = -n;
        if (n > SEQ - 1) n = 2 * (SEQ - 1) - n;
        *(float4*)&xs[r][c4] =
            *(const float4*)&x[((size_t)(b * SEQ + n)) * D_MODEL + d0 + c4];
    }
    float a0 = alpha[0], a1 = alpha[1], a2 = alpha[2];
    float mx = fmaxf(a0, fmaxf(a1, a2));
    float e0 = __expf(a0 - mx), e1 = __expf(a1 - mx), e2 = __expf(a2 - mx);
    float inv = 1.0f / (e0 + e1 + e2);
    float w7 = e0 * inv, w25 = e1 * inv, w49 = e2 * inv;
    const int dl = threadIdx.x & 63;
    const int nt = threadIdx.x >> 6;
    const int d = d0 + dl;
    float w[49];
    #pragma unroll
    for (int j = 0; j < 49; j++) {
        float v = w49 * dw49[d * 49 + j];
        if (j >= 12 && j < 37) v += w25 * dw25[d * 25 + j - 12];
        if (j >= 21 && j < 28) v += w7 * dw7[d * 7 + j - 21];
        w[j] = v;
    }
    __syncthreads();
    for (int nl = nt; nl < TN; nl += 4) {
        float acc = 0.f;
        #pragma unroll
        for (int j = 0; j < 49; j++) acc = fmaf(xs[nl + j][dl], w[j], acc);
        size_t idx = ((size_t)(b * SEQ + n0 + nl)) * D_MODEL + d;
        Tr[idx] = acc;
        S[idx] = xs[nl + 24][dl] - acc;
    }
}

// ---------------- LayerNorm (fp32 in, bf16 out, optional fp32 out) ----------------
__global__ __launch_bounds__(256) void ln_k(
    const float* __restrict__ x, const float* __restrict__ g, const float* __restrict__ b,
    bf16* __restrict__ ob, float* __restrict__ of)
{
    int row = blockIdx.x, t = threadIdx.x;
    const float* xr = x + (size_t)row * D_MODEL;
    float s = 0.f, s2 = 0.f;
    for (int d = t; d < D_MODEL; d += 256) { float v = xr[d]; s += v; s2 += v * v; }
    #pragma unroll
    for (int o = 32; o > 0; o >>= 1) { s += __shfl_down(s, o); s2 += __shfl_down(s2, o); }
    __shared__ float sh[8];
    int wid = t >> 6, lane = t & 63;
    if (lane == 0) { sh[wid] = s; sh[4 + wid] = s2; }
    __syncthreads();
    if (t == 0) {
        float ts = sh[0] + sh[1] + sh[2] + sh[3];
        float t2 = sh[4] + sh[5] + sh[6] + sh[7];
        float m = ts / D_MODEL;
        float var = t2 / D_MODEL - m * m;
        sh[0] = m; sh[1] = rsqrtf(var + 1e-5f);
    }
    __syncthreads();
    float m = sh[0], rs = sh[1];
    for (int d = t; d < D_MODEL; d += 256) {
        float v = (xr[d] - m) * rs * g[d] + b[d];
        ob[(size_t)row * D_MODEL + d] = __float2bfloat16(v);
        if (of) of[(size_t)row * D_MODEL + d] = v;
    }
}

// ---------------- bf16 MFMA GEMM: C[M,O] = A[M,K] @ B[O,K]^T (+bias)(+act) ----------------
// 512 threads = 8 waves; block tile 128x128; wave tile 32x64; acc[2][4]=32 regs.
// Reg budget <=128 unified (launch_bounds 512,4) -> 4 waves/SIMD = 2 blocks/CU.
// OMODE 0: fp32 out (+resid), 1: bf16 out (compact at off+row for GMODE1), 2: fp32 atomicAdd scatter
// GMODE 0: dense; 1: gather A rows via row_map, store compact; 2: dense compact A, scatter-atomic store
// GMODE!=0: blockIdx.z = expert. T14: next tile's global loads issued during compute.
template<int ACT, int OMODE, int GMODE>
__global__ __launch_bounds__(512, 4) void gemm_nt(
    const bf16* __restrict__ A, const bf16* __restrict__ B,
    const float* __restrict__ bias, const float* resid,
    const float* __restrict__ rowscale, int rs_stride,
    void* C, int M, int K, int O,
    const int* __restrict__ row_map, const int* __restrict__ cnt_ptr,
    const int* __restrict__ off_ptr, size_t b_estride, int bias_estride)
{
    const int bm = blockIdx.x, bn = blockIdx.y;
    const int e = (GMODE != 0) ? blockIdx.z : 0;
    int M_act = M;
    int off = 0;
    const int* rmap = row_map;
    if (GMODE != 0) {
        M_act = cnt_ptr[e];
        if (bm * 128 >= M_act) return;
        off = off_ptr[e];
        rmap = row_map + e * TOKENS;
        B += (size_t)e * b_estride;
        if (bias) bias += (size_t)e * bias_estride;
    }
    __shared__ bf16 As[128][72];
    __shared__ bf16 Bs[128][72];
    const int t = threadIdx.x;
    const int lane = t & 63, wid = t >> 6;   // wid 0..7
    const int wm = wid >> 1, wn = wid & 1;   // wm: 32-row strip, wn: 64-col strip
    f32x4 acc[2][4] = {};
    const int lr = t >> 3;          // 0..63
    const int lc = (t & 7) * 8;     // 0..56
    const size_t abase = (GMODE == 2) ? (size_t)(off + bm * 128) * K : (size_t)(bm * 128) * K;
    const size_t bbase = (size_t)(bn * 128) * K;
    size_t arow[2];
    #pragma unroll
    for (int p = 0; p < 2; p++) {
        int r = p * 64 + lr;
        if (GMODE == 1) {
            int gr = bm * 128 + r;
            arow[p] = (size_t)rmap[gr < M_act ? gr : M_act - 1] * K;
        } else {
            arow[p] = abase + (size_t)r * K;
        }
    }
    // prologue: load tile 0 into regs
    s8v ra[2], rb[2];
    #pragma unroll
    for (int p = 0; p < 2; p++) {
        ra[p] = *(const s8v*)&A[arow[p] + lc];
        rb[p] = *(const s8v*)&B[bbase + (size_t)(p * 64 + lr) * K + lc];
    }
    for (int k0 = 0; k0 < K; k0 += 64) {
        #pragma unroll
        for (int p = 0; p < 2; p++) {
            int r = p * 64 + lr;
            *(s8v*)&As[r][lc] = ra[p];
            *(s8v*)&Bs[r][lc] = rb[p];
        }
        __syncthreads();
        // T14: issue next tile's loads; latency hides under compute + barrier
        if (k0 + 64 < K) {
            const int kn = k0 + 64 + lc;
            #pragma unroll
            for (int p = 0; p < 2; p++) {
                ra[p] = *(const s8v*)&A[arow[p] + kn];
                rb[p] = *(const s8v*)&B[bbase + (size_t)(p * 64 + lr) * K + kn];
            }
        }
        const int fr = lane & 15, fq = (lane >> 4) * 8;
        #pragma unroll
        for (int kk = 0; kk < 64; kk += 32) {
            s8v af[2], bfr[4];
            #pragma unroll
            for (int i = 0; i < 2; i++)
                af[i] = *(const s8v*)&As[wm * 32 + i * 16 + fr][kk + fq];
            #pragma unroll
            for (int j = 0; j < 4; j++)
                bfr[j] = *(const s8v*)&Bs[wn * 64 + j * 16 + fr][kk + fq];
            #pragma unroll
            for (int i = 0; i < 2; i++)
                #pragma unroll
                for (int j = 0; j < 4; j++)
                    acc[i][j] = __builtin_amdgcn_mfma_f32_16x16x32_bf16(af[i], bfr[j], acc[i][j], 0, 0, 0);
        }
        __syncthreads();
    }
    const int cr = lane & 15, quad = lane >> 4;
    #pragma unroll
    for (int i = 0; i < 2; i++) {
        #pragma unroll
        for (int r = 0; r < 4; r++) {
            int row = bm * 128 + wm * 32 + i * 16 + quad * 4 + r;
            if (GMODE != 0 && row >= M_act) continue;
            int srow = (GMODE == 2) ? rmap[row] : ((GMODE == 1) ? off + row : row);
            #pragma unroll
            for (int j = 0; j < 4; j++) {
                int col = bn * 128 + wn * 64 + j * 16 + cr;
                float v = acc[i][j][r];
                if (bias) v += bias[col];
                if (ACT == 1) v = 0.5f * v * (1.0f + erff(v * 0.70710678118f));
                size_t idx = (size_t)srow * O + col;
                if (OMODE == 0) {
                    float rv = resid ? resid[idx] : 0.0f;
                    ((float*)C)[idx] = rv + v;
                } else if (OMODE == 1) {
                    ((bf16*)C)[idx] = __float2bfloat16(v);
                } else {
                    atomicAdd(&((float*)C)[idx], rowscale[(size_t)srow * rs_stride + e] * v);
                }
            }
        }
    }
}

// ---------------- MFMA flash attention with ALiBi, fixed-shift softmax ----------------
// block: 256 thr = 4 waves, each wave owns 32 q-rows (128 q-rows/block)
// reads packed QKV [tokens, 3072]; T14 async-stage; log2-domain softmax
__global__ __launch_bounds__(256) void attn_k(
    const bf16* __restrict__ QKV, bf16* __restrict__ Y)
{
    __shared__ bf16 Ks[64][72];
    __shared__ bf16 Vt[64][66];
    __shared__ bf16 Pw[4][32][72];
    const int t = threadIdx.x;
    const int wave = t >> 6, lane = t & 63;
    const int qm = lane & 15, quad = lane >> 4;
    const int b = blockIdx.z, h = blockIdx.y;
    const int qbase = blockIdx.x * 128 + wave * 32;
    const float LOG2E = 1.44269504f;
    const float slope2 = exp2f(-0.5f * (float)(h + 1)) * LOG2E;   // slope * log2(e)
    const float NEG8L2 = -11.54156036f;                            // -8 * log2(e)
    const float SCL2   = 0.18033688f;                              // 0.125 * log2(e)

    s8v qa[2][2];
    #pragma unroll
    for (int g = 0; g < 2; g++) {
        const bf16* qp = QKV + ((size_t)(b * SEQ + qbase + g * 16 + qm)) * QKV_S + h * HD;
        qa[g][0] = *(const s8v*)&qp[quad * 8];
        qa[g][1] = *(const s8v*)&qp[32 + quad * 8];
    }
    float aqp[2][4];
    #pragma unroll
    for (int g = 0; g < 2; g++)
        #pragma unroll
        for (int r = 0; r < 4; r++)
            aqp[g][r] = slope2 * (float)(qbase + g * 16 + quad * 4 + r) + NEG8L2;

    f32x4 o[2][4] = {};
    float l[2][4] = {};

    const int sr = t >> 2;
    const int scc = (t & 3) * 16;
    // base for this lane's K row slice; V is +1024 from K within the packed row
    const bf16* kvb = QKV + (size_t)(b * SEQ) * QKV_S + D_MODEL + h * HD + scc;

    {
        const bf16* p0 = kvb + (size_t)sr * QKV_S;
        s8v k0v = *(const s8v*)&p0[0];
        s8v k1v = *(const s8v*)&p0[8];
        s8v v0  = *(const s8v*)&p0[D_MODEL];
        s8v v1  = *(const s8v*)&p0[D_MODEL + 8];

        for (int k0 = 0; k0 < SEQ; k0 += 64) {
            *(s8v*)&Ks[sr][scc] = k0v;
            *(s8v*)&Ks[sr][scc + 8] = k1v;
            #pragma unroll
            for (int j = 0; j < 8; j++) {
                Vt[scc + j][sr]     = ((const bf16*)&v0)[j];
                Vt[scc + 8 + j][sr] = ((const bf16*)&v1)[j];
            }
            __syncthreads();
            if (k0 + 64 < SEQ) {   // T14: issue next tile's loads; latency hides under compute
                const bf16* np = kvb + (size_t)(k0 + 64 + sr) * QKV_S;
                k0v = *(const s8v*)&np[0];
                k1v = *(const s8v*)&np[8];
                v0  = *(const s8v*)&np[D_MODEL];
                v1  = *(const s8v*)&np[D_MODEL + 8];
            }
            float bk[4];
            #pragma unroll
            for (int jt = 0; jt < 4; jt++) bk[jt] = slope2 * (float)(k0 + jt * 16 + qm);
            #pragma unroll
            for (int g = 0; g < 2; g++) {
                f32x4 scr[4];
                #pragma unroll
                for (int jt = 0; jt < 4; jt++) {
                    f32x4 z = {};
                    s8v b0 = *(const s8v*)&Ks[jt * 16 + qm][quad * 8];
                    s8v b1 = *(const s8v*)&Ks[jt * 16 + qm][32 + quad * 8];
                    z = __builtin_amdgcn_mfma_f32_16x16x32_bf16(qa[g][0], b0, z, 0, 0, 0);
                    z = __builtin_amdgcn_mfma_f32_16x16x32_bf16(qa[g][1], b1, z, 0, 0, 0);
                    scr[jt] = z;
                }
                #pragma unroll
                for (int jt = 0; jt < 4; jt++) {
                    #pragma unroll
                    for (int r = 0; r < 4; r++) {
                        float term = fminf(aqp[g][r] - bk[jt], NEG8L2);
                        float pf = exp2f(fmaf(scr[jt][r], SCL2, term));
                        bf16 pb = __float2bfloat16(pf);
                        l[g][r] += __bfloat162float(pb);
                        Pw[wave][g * 16 + quad * 4 + r][jt * 16 + qm] = pb;
                    }
                }
            }
            __builtin_amdgcn_wave_barrier();
            #pragma unroll
            for (int g = 0; g < 2; g++) {
                s8v pa0 = *(const s8v*)&Pw[wave][g * 16 + qm][quad * 8];
                s8v pa1 = *(const s8v*)&Pw[wave][g * 16 + qm][32 + quad * 8];
                #pragma unroll
                for (int dt = 0; dt < 4; dt++) {
                    s8v vb0 = *(const s8v*)&Vt[dt * 16 + qm][quad * 8];
                    s8v vb1 = *(const s8v*)&Vt[dt * 16 + qm][32 + quad * 8];
                    o[g][dt] = __builtin_amdgcn_mfma_f32_16x16x32_bf16(pa0, vb0, o[g][dt], 0, 0, 0);
                    o[g][dt] = __builtin_amdgcn_mfma_f32_16x16x32_bf16(pa1, vb1, o[g][dt], 0, 0, 0);
                }
            }
            __syncthreads();
        }
    }
    #pragma unroll
    for (int g = 0; g < 2; g++)
        #pragma unroll
        for (int r = 0; r < 4; r++) {
            float s = l[g][r];
            s += __shfl_xor(s, 1); s += __shfl_xor(s, 2);
            s += __shfl_xor(s, 4); s += __shfl_xor(s, 8);
            l[g][r] = 1.0f / s;
        }
    #pragma unroll
    for (int g = 0; g < 2; g++)
        #pragma unroll
        for (int dt = 0; dt < 4; dt++)
            #pragma unroll
            for (int r = 0; r < 4; r++) {
                size_t idx = ((size_t)(b * SEQ + qbase + g * 16 + quad * 4 + r)) * D_MODEL + h * HD + dt * 16 + qm;
                Y[idx] = __float2bfloat16(o[g][dt][r] * l[g][r]);
            }
}

// ---------------- router: gates, top-2 weights, aux, per-expert token lists ----------------
__global__ __launch_bounds__(256) void router_k(
    const float* __restrict__ xf, const float* __restrict__ rw,
    float* __restrict__ wts, float* __restrict__ auxb,
    int* __restrict__ cnt, int* __restrict__ elist)
{
    const int wave = threadIdx.x >> 6, lane = threadIdx.x & 63;
    float4 w[4][4];
    #pragma unroll
    for (int e = 0; e < 4; e++)
        #pragma unroll
        for (int c = 0; c < 4; c++)
            w[e][c] = *(const float4*)&rw[e * D_MODEL + lane * 16 + c * 4];
    float ag[4] = {0.f, 0.f, 0.f, 0.f};
    float ac[4] = {0.f, 0.f, 0.f, 0.f};
    __shared__ int sel[16][2];
    __shared__ float sh[4][8];
    const int t0 = (blockIdx.x * 4 + wave) * 4;
    #pragma unroll
    for (int i = 0; i < 4; i++) {
        const int tk = t0 + i;
        const float* xr = xf + (size_t)tk * D_MODEL + lane * 16;
        float4 xv[4];
        #pragma unroll
        for (int c = 0; c < 4; c++) xv[c] = *(const float4*)&xr[c * 4];
        float p[4] = {0.f, 0.f, 0.f, 0.f};
        #pragma unroll
        for (int e = 0; e < 4; e++)
            #pragma unroll
            for (int c = 0; c < 4; c++) {
                p[e] = fmaf(xv[c].x, w[e][c].x, p[e]);
                p[e] = fmaf(xv[c].y, w[e][c].y, p[e]);
                p[e] = fmaf(xv[c].z, w[e][c].z, p[e]);
                p[e] = fmaf(xv[c].w, w[e][c].w, p[e]);
            }
        #pragma unroll
        for (int o = 1; o < 64; o <<= 1) {
            p[0] += __shfl_xor(p[0], o); p[1] += __shfl_xor(p[1], o);
            p[2] += __shfl_xor(p[2], o); p[3] += __shfl_xor(p[3], o);
        }
        float g[4];
        float mx = fmaxf(fmaxf(p[0], p[1]), fmaxf(p[2], p[3]));
        float se = 0.f;
        #pragma unroll
        for (int e = 0; e < 4; e++) { g[e] = __expf(p[e] - mx); se += g[e]; }
        #pragma unroll
        for (int e = 0; e < 4; e++) g[e] /= se;
        int i1 = 0; float v1 = g[0];
        #pragma unroll
        for (int e = 1; e < 4; e++) if (g[e] > v1) { v1 = g[e]; i1 = e; }
        int i2 = -1; float v2 = -1.f;
        #pragma unroll
        for (int e = 0; e < 4; e++) if (e != i1 && g[e] > v2) { v2 = g[e]; i2 = e; }
        float sw = fmaxf(v1 + v2, 1e-9f);
        if (lane < 4) {
            float wv = (lane == i1) ? v1 / sw : ((lane == i2) ? v2 / sw : 0.f);
            wts[(size_t)tk * 4 + lane] = wv;
        }
        if (lane == 0) {
            #pragma unroll
            for (int e = 0; e < 4; e++) ag[e] += g[e];
            ac[i1] += 1.f; ac[i2] += 1.f;
            sel[wave * 4 + i][0] = i1;
            sel[wave * 4 + i][1] = i2;
        }
    }
    if (lane == 0)
        #pragma unroll
        for (int e = 0; e < 4; e++) { sh[wave][e] = ag[e]; sh[wave][4 + e] = ac[e]; }
    __syncthreads();
    if (threadIdx.x < 8) {
        float s = sh[0][threadIdx.x] + sh[1][threadIdx.x] + sh[2][threadIdx.x] + sh[3][threadIdx.x];
        atomicAdd(&auxb[threadIdx.x], s);
    }
    if (threadIdx.x < 4) {
        const int e = threadIdx.x;
        int loc[16]; int c = 0;
        #pragma unroll
        for (int s = 0; s < 16; s++)
            if (sel[s][0] == e || sel[s][1] == e) loc[c++] = blockIdx.x * 16 + s;
        if (c) {
            int base = atomicAdd(&cnt[e], c);
            for (int k = 0; k < c; k++) elist[e * TOKENS + base + k] = loc[k];
        }
    }
}

// ---------------- final: out = x_s + depthwise-conv5(Tr) + tb ----------------
__global__ __launch_bounds__(256) void final_k(
    const float* __restrict__ xs, const float* __restrict__ Tr,
    const float* __restrict__ tw, const float* __restrict__ tb, float* __restrict__ out)
{
    int n = blockIdx.x, b = blockIdx.y, t = threadIdx.x;
    for (int d = t; d < D_MODEL; d += 256) {
        float acc = tb[d];
        #pragma unroll
        for (int j = 0; j < 5; j++) {
            int i = n + j - 2;
            if (i >= 0 && i < SEQ)
                acc += Tr[((size_t)(b * SEQ + i)) * D_MODEL + d] * tw[d * 5 + j];
        }
        size_t idx = ((size_t)(b * SEQ + n)) * D_MODEL + d;
        out[idx] = xs[idx] + acc;
    }
}

__global__ void aux_k(const float* __restrict__ ab, float* __restrict__ out) {
    if (threadIdx.x == 0 && blockIdx.x == 0) {
        float a = 0.f;
        for (int e = 0; e < 4; e++)
            a += (ab[e] / (float)TOKENS) * (ab[4 + e] / (float)TOKENS);
        out[0] = 4.0f * a;
    }
}

extern "C" void kernel_launch(void* const* d_in, const int* in_sizes, int n_in,
                              void* d_out, int out_size, void* d_ws, size_t ws_size,
                              hipStream_t stream)
{
    const float* x    = (const float*)d_in[0];
    const float* qw   = (const float*)d_in[1];
    const float* qb   = (const float*)d_in[2];
    const float* kw   = (const float*)d_in[3];
    const float* kb   = (const float*)d_in[4];
    const float* vw   = (const float*)d_in[5];
    const float* vb   = (const float*)d_in[6];
    const float* ow   = (const float*)d_in[7];
    const float* ob   = (const float*)d_in[8];
    const float* n1g  = (const float*)d_in[9];
    const float* n1b  = (const float*)d_in[10];
    const float* n2g  = (const float*)d_in[11];
    const float* n2b  = (const float*)d_in[12];
    const float* alpha= (const float*)d_in[13];
    const float* dw7  = (const float*)d_in[14];
    const float* dw25 = (const float*)d_in[15];
    const float* dw49 = (const float*)d_in[16];
    const float* rw   = (const float*)d_in[17];
    const float* ew1  = (const float*)d_in[18];
    const float* eb1  = (const float*)d_in[19];
    const float* ew2  = (const float*)d_in[20];
    const float* eb2  = (const float*)d_in[21];
    const float* tw   = (const float*)d_in[22];
    const float* tb   = (const float*)d_in[23];

    char* ws = (char*)d_ws;
    const size_t MBy = 1ull << 20;
    float* S    = (float*)(ws + 0 * MBy);
    float* Tr   = (float*)(ws + 32 * MBy);
    float* XF   = (float*)(ws + 64 * MBy);
    bf16*  SNB  = (bf16*)(ws + 96 * MBy);    // [8192,1024] bf16; also attn Y
    bf16*  QKVB = (bf16*)(ws + 112 * MBy);   // [8192, 3072] packed Q|K|V (112..160)
    bf16*  XFB  = (bf16*)(ws + 160 * MBy);
    bf16*  WQ   = (bf16*)(ws + 176 * MBy);   // WQ|WK|WV contiguous = fused [3072,1024]
    bf16*  WK   = (bf16*)(ws + 178 * MBy);
    bf16*  WV   = (bf16*)(ws + 180 * MBy);
    bf16*  WO   = (bf16*)(ws + 182 * MBy);
    bf16*  WE1  = (bf16*)(ws + 184 * MBy);
    bf16*  WE2  = (bf16*)(ws + 200 * MBy);
    float* WTS  = (float*)(ws + 216 * MBy);
    float* AUXB = (float*)(ws + 217 * MBy);           // 8 floats
    int*   CNT  = (int*)(AUXB + 8);                   // 4 ints
    int*   OFF  = CNT + 4;                            // 4 ints (prefix sums)
    float* QKVBIAS = (float*)(ws + 217 * MBy + 4096); // 3072 floats
    int*   ELST = (int*)(ws + 218 * MBy);             // 4 * 8192 ints
    bf16*  YB = SNB;
    // compact MoE hidden: 16384 rows x 2048 bf16 = 64 MiB, reuses dead SNB+QKVB (96..160)
    bf16*  HALL = (bf16*)(ws + 96 * MBy);

    f2b_k<<<2048, 256, 0, stream>>>(qw, WQ, D_MODEL * D_MODEL);
    f2b_k<<<2048, 256, 0, stream>>>(kw, WK, D_MODEL * D_MODEL);
    f2b_k<<<2048, 256, 0, stream>>>(vw, WV, D_MODEL * D_MODEL);
    f2b_k<<<2048, 256, 0, stream>>>(ow, WO, D_MODEL * D_MODEL);
    f2b_k<<<4096, 256, 0, stream>>>(ew1, WE1, 4 * MOE_H * D_MODEL);
    f2b_k<<<4096, 256, 0, stream>>>(ew2, WE2, 4 * D_MODEL * MOE_H);
    cat3_k<<<12, 256, 0, stream>>>(qb, kb, vb, QKVBIAS);

    decomp_k<<<dim3(SEQ / TN, D_MODEL / TD, NB), 256, 0, stream>>>(x, alpha, dw7, dw25, dw49, Tr, S);

    ln_k<<<TOKENS, 256, 0, stream>>>(S, n1g, n1b, SNB, nullptr);

    // fused QKV projection: [8192,1024] @ [3072,1024]^T -> [8192,3072]
    gemm_nt<0, 1, 0><<<dim3(64, 24), 512, 0, stream>>>(SNB, WQ, QKVBIAS, nullptr, nullptr, 0, QKVB, TOKENS, D_MODEL, QKV_S, nullptr, nullptr, nullptr, 0, 0);

    attn_k<<<dim3(SEQ / 128, NHEAD, NB), 256, 0, stream>>>(QKVB, YB);

    gemm_nt<0, 0, 0><<<dim3(64, 8), 512, 0, stream>>>(YB, WO, ob, S, nullptr, 0, S, TOKENS, D_MODEL, D_MODEL, nullptr, nullptr, nullptr, 0, 0);

    ln_k<<<TOKENS, 256, 0, stream>>>(S, n2g, n2b, XFB, XF);

    hipMemsetAsync(AUXB, 0, 64, stream);
    router_k<<<TOKENS / 16, 256, 0, stream>>>(XF, rw, WTS, AUXB, CNT, ELST);
    prefix_k<<<1, 64, 0, stream>>>(CNT, OFF);

    // sparse top-2 MoE, all experts batched via blockIdx.z
    // up: XFB gathered -> HALL compact (gelu);   down: HALL -> S (atomic scatter-add)
    gemm_nt<1, 1, 1><<<dim3(64, MOE_H / 128, 4), 512, 0, stream>>>(
        XFB, WE1, eb1, nullptr, nullptr, 0, HALL, TOKENS, D_MODEL, MOE_H,
        ELST, CNT, OFF, (size_t)MOE_H * D_MODEL, MOE_H);
    gemm_nt<0, 2, 2><<<dim3(64, D_MODEL / 128, 4), 512, 0, stream>>>(
        HALL, WE2, eb2, nullptr, WTS, 4, S, TOKENS, MOE_H, D_MODEL,
        ELST, CNT, OFF, (size_t)D_MODEL * MOE_H, D_MODEL);

    final_k<<<dim3(SEQ, NB), 256, 0, stream>>>(S, Tr, tw, tb, (float*)d_out);
    aux_k<<<1, 64, 0, stream>>>(AUXB, (float*)d_out + (out_size - 1));
}

// Round 7
// 858.543 us; speedup vs baseline: 1.3928x; 1.0361x over previous
//
#include <hip/hip_runtime.h>
#include <hip/hip_bf16.h>
#include <math.h>

using bf16 = __hip_bfloat16;
typedef __attribute__((ext_vector_type(8))) short s8v;
typedef __attribute__((ext_vector_type(4))) float f32x4;

#define D_MODEL 1024
#define NB 8
#define SEQ 1024
#define NHEAD 16
#define HD 64
#define MOE_H 2048
#define TOKENS (NB*SEQ)
#define QKV_S 3072   // fused QKV row stride

// ---------------- fp32 -> bf16 convert ----------------
__global__ void f2b_k(const float* __restrict__ in, bf16* __restrict__ out, int n) {
    int i = blockIdx.x * blockDim.x + threadIdx.x;
    int stride = gridDim.x * blockDim.x;
    for (; i < n; i += stride) out[i] = __float2bfloat16(in[i]);
}

// concat 3x1024 bias vectors into one 3072 buffer
__global__ void cat3_k(const float* __restrict__ a, const float* __restrict__ b,
                       const float* __restrict__ c, float* __restrict__ o) {
    int i = blockIdx.x * blockDim.x + threadIdx.x;
    if (i < 1024) o[i] = a[i];
    else if (i < 2048) o[i] = b[i - 1024];
    else if (i < 3072) o[i] = c[i - 2048];
}

// prefix sums of the 4 expert counts
__global__ void prefix_k(const int* __restrict__ cnt, int* __restrict__ off) {
    if (threadIdx.x == 0 && blockIdx.x == 0) {
        int s = 0;
        for (int e = 0; e < 4; e++) { off[e] = s; s += cnt[e]; }
    }
}

// ---------------- decomposition: trend + seasonal (LDS-tiled stencil) ----------------
#define TN 128
#define TD 64
__global__ __launch_bounds__(256) void decomp_k(
    const float* __restrict__ x, const float* __restrict__ alpha,
    const float* __restrict__ dw7, const float* __restrict__ dw25,
    const float* __restrict__ dw49, float* __restrict__ Tr, float* __restrict__ S)
{
    __shared__ float xs[TN + 48][TD];
    const int n0 = blockIdx.x * TN, d0 = blockIdx.y * TD, b = blockIdx.z;
    for (int i = threadIdx.x; i < (TN + 48) * (TD / 4); i += 256) {
        int r = i / (TD / 4), c4 = (i % (TD / 4)) * 4;
        int n = n0 + r - 24;
        if (n < 0) n = -n;
        if (n > SEQ - 1) n = 2 * (SEQ - 1) - n;
        *(float4*)&xs[r][c4] =
            *(const float4*)&x[((size_t)(b * SEQ + n)) * D_MODEL + d0 + c4];
    }
    float a0 = alpha[0], a1 = alpha[1], a2 = alpha[2];
    float mx = fmaxf(a0, fmaxf(a1, a2));
    float e0 = __expf(a0 - mx), e1 = __expf(a1 - mx), e2 = __expf(a2 - mx);
    float inv = 1.0f / (e0 + e1 + e2);
    float w7 = e0 * inv, w25 = e1 * inv, w49 = e2 * inv;
    const int dl = threadIdx.x & 63;
    const int nt = threadIdx.x >> 6;
    const int d = d0 + dl;
    float w[49];
    #pragma unroll
    for (int j = 0; j < 49; j++) {
        float v = w49 * dw49[d * 49 + j];
        if (j >= 12 && j < 37) v += w25 * dw25[d * 25 + j - 12];
        if (j >= 21 && j < 28) v += w7 * dw7[d * 7 + j - 21];
        w[j] = v;
    }
    __syncthreads();
    for (int nl = nt; nl < TN; nl += 4) {
        float acc = 0.f;
        #pragma unroll
        for (int j = 0; j < 49; j++) acc = fmaf(xs[nl + j][dl], w[j], acc);
        size_t idx = ((size_t)(b * SEQ + n0 + nl)) * D_MODEL + d;
        Tr[idx] = acc;
        S[idx] = xs[nl + 24][dl] - acc;
    }
}

// ---------------- LayerNorm (fp32 in, bf16 out, optional fp32 out) ----------------
__global__ __launch_bounds__(256) void ln_k(
    const float* __restrict__ x, const float* __restrict__ g, const float* __restrict__ b,
    bf16* __restrict__ ob, float* __restrict__ of)
{
    int row = blockIdx.x, t = threadIdx.x;
    const float* xr = x + (size_t)row * D_MODEL;
    float s = 0.f, s2 = 0.f;
    for (int d = t; d < D_MODEL; d += 256) { float v = xr[d]; s += v; s2 += v * v; }
    #pragma unroll
    for (int o = 32; o > 0; o >>= 1) { s += __shfl_down(s, o); s2 += __shfl_down(s2, o); }
    __shared__ float sh[8];
    int wid = t >> 6, lane = t & 63;
    if (lane == 0) { sh[wid] = s; sh[4 + wid] = s2; }
    __syncthreads();
    if (t == 0) {
        float ts = sh[0] + sh[1] + sh[2] + sh[3];
        float t2 = sh[4] + sh[5] + sh[6] + sh[7];
        float m = ts / D_MODEL;
        float var = t2 / D_MODEL - m * m;
        sh[0] = m; sh[1] = rsqrtf(var + 1e-5f);
    }
    __syncthreads();
    float m = sh[0], rs = sh[1];
    for (int d = t; d < D_MODEL; d += 256) {
        float v = (xr[d] - m) * rs * g[d] + b[d];
        ob[(size_t)row * D_MODEL + d] = __float2bfloat16(v);
        if (of) of[(size_t)row * D_MODEL + d] = v;
    }
}

// ---------------- bf16 MFMA GEMM: C[M,O] = A[M,K] @ B[O,K]^T (+bias)(+act) ----------------
// 512 threads = 8 waves; block tile 128x128; wave tile 32x64; acc[2][4]=32 regs.
// 2-phase pipeline: double-buffered LDS, raw s_barrier (NO vmcnt drain), 2-deep reg prefetch.
// One barrier per K-step; prefetch loads stay in flight across barriers (counted vmcnt).
// OMODE 0: fp32 out (+resid), 1: bf16 out (compact at off+row for GMODE1), 2: fp32 atomicAdd scatter
// GMODE 0: dense; 1: gather A rows via row_map, store compact; 2: dense compact A, scatter-atomic store
// GMODE!=0: blockIdx.z = expert.
template<int ACT, int OMODE, int GMODE>
__global__ __launch_bounds__(512, 4) void gemm_nt(
    const bf16* __restrict__ A, const bf16* __restrict__ B,
    const float* __restrict__ bias, const float* resid,
    const float* __restrict__ rowscale, int rs_stride,
    void* C, int M, int K, int O,
    const int* __restrict__ row_map, const int* __restrict__ cnt_ptr,
    const int* __restrict__ off_ptr, size_t b_estride, int bias_estride)
{
    const int bm = blockIdx.x, bn = blockIdx.y;
    const int e = (GMODE != 0) ? blockIdx.z : 0;
    int M_act = M;
    int off = 0;
    const int* rmap = row_map;
    if (GMODE != 0) {
        M_act = cnt_ptr[e];
        if (bm * 128 >= M_act) return;
        off = off_ptr[e];
        rmap = row_map + e * TOKENS;
        B += (size_t)e * b_estride;
        if (bias) bias += (size_t)e * bias_estride;
    }
    __shared__ bf16 As[2][128][72];
    __shared__ bf16 Bs[2][128][72];
    const int t = threadIdx.x;
    const int lane = t & 63, wid = t >> 6;   // wid 0..7
    const int wm = wid >> 1, wn = wid & 1;   // wm: 32-row strip, wn: 64-col strip
    f32x4 acc[2][4] = {};
    const int lr = t >> 3;          // 0..63
    const int lc = (t & 7) * 8;     // 0..56
    const size_t abase = (GMODE == 2) ? (size_t)(off + bm * 128) * K : (size_t)(bm * 128) * K;
    const size_t bbase = (size_t)(bn * 128) * K;
    size_t arow[2];
    #pragma unroll
    for (int p = 0; p < 2; p++) {
        int r = p * 64 + lr;
        if (GMODE == 1) {
            int gr = bm * 128 + r;
            arow[p] = (size_t)rmap[gr < M_act ? gr : M_act - 1] * K;
        } else {
            arow[p] = abase + (size_t)r * K;
        }
    }
    const int nt = K / 64;   // >= 16 for all shapes here, always even

#define LOADT(RA, RB, TT) do { const int kn_ = (TT) * 64 + lc;                      \
    _Pragma("unroll") for (int p_ = 0; p_ < 2; p_++) {                              \
        RA[p_] = *(const s8v*)&A[arow[p_] + kn_];                                   \
        RB[p_] = *(const s8v*)&B[bbase + (size_t)(p_ * 64 + lr) * K + kn_]; } } while (0)
#define WRITET(BUF, RA, RB) do {                                                    \
    _Pragma("unroll") for (int p_ = 0; p_ < 2; p_++) {                              \
        *(s8v*)&As[BUF][p_ * 64 + lr][lc] = RA[p_];                                 \
        *(s8v*)&Bs[BUF][p_ * 64 + lr][lc] = RB[p_]; } } while (0)
#define LBAR() do { asm volatile("s_waitcnt lgkmcnt(0)" ::: "memory");              \
    __builtin_amdgcn_sched_barrier(0); __builtin_amdgcn_s_barrier(); } while (0)
#define COMPUTE(BUF) do {                                                           \
    _Pragma("unroll") for (int kk_ = 0; kk_ < 64; kk_ += 32) {                      \
        s8v af_[2], bf_[4];                                                         \
        _Pragma("unroll") for (int i_ = 0; i_ < 2; i_++)                            \
            af_[i_] = *(const s8v*)&As[BUF][wm * 32 + i_ * 16 + fr][kk_ + fq];      \
        _Pragma("unroll") for (int j_ = 0; j_ < 4; j_++)                            \
            bf_[j_] = *(const s8v*)&Bs[BUF][wn * 64 + j_ * 16 + fr][kk_ + fq];      \
        _Pragma("unroll") for (int i_ = 0; i_ < 2; i_++)                            \
            _Pragma("unroll") for (int j_ = 0; j_ < 4; j_++)                        \
                acc[i_][j_] = __builtin_amdgcn_mfma_f32_16x16x32_bf16(af_[i_], bf_[j_], acc[i_][j_], 0, 0, 0); \
    } } while (0)

    const int fr = lane & 15, fq = (lane >> 4) * 8;
    // pipeline regs: r0 = even tiles, r1 = odd tiles (static names, rule #20)
    s8v r0a[2], r0b[2], r1a[2], r1b[2];
    LOADT(r0a, r0b, 0);
    WRITET(0, r0a, r0b);
    LOADT(r1a, r1b, 1);   // issued before r0's tile-2 loads: consumed first
    LOADT(r0a, r0b, 2);
    LBAR();               // buf0 visible to all waves; prefetches stay in flight

    for (int tt = 0; tt < nt; tt += 2) {
        // even step: stage tile tt+1 -> buf1, prefetch tile tt+3, compute buf0
        WRITET(1, r1a, r1b);                       // compiler waits counted vmcnt for r1 only
        if (tt + 3 < nt) LOADT(r1a, r1b, tt + 3);
        COMPUTE(0);
        LBAR();
        // odd step: stage tile tt+2 -> buf0, prefetch tile tt+4, compute buf1
        if (tt + 2 < nt) {
            WRITET(0, r0a, r0b);
            if (tt + 4 < nt) LOADT(r0a, r0b, tt + 4);
        }
        COMPUTE(1);
        LBAR();
    }
#undef LOADT
#undef WRITET
#undef LBAR
#undef COMPUTE

    const int cr = lane & 15, quad = lane >> 4;
    #pragma unroll
    for (int i = 0; i < 2; i++) {
        #pragma unroll
        for (int r = 0; r < 4; r++) {
            int row = bm * 128 + wm * 32 + i * 16 + quad * 4 + r;
            if (GMODE != 0 && row >= M_act) continue;
            int srow = (GMODE == 2) ? rmap[row] : ((GMODE == 1) ? off + row : row);
            #pragma unroll
            for (int j = 0; j < 4; j++) {
                int col = bn * 128 + wn * 64 + j * 16 + cr;
                float v = acc[i][j][r];
                if (bias) v += bias[col];
                if (ACT == 1) v = 0.5f * v * (1.0f + erff(v * 0.70710678118f));
                size_t idx = (size_t)srow * O + col;
                if (OMODE == 0) {
                    float rv = resid ? resid[idx] : 0.0f;
                    ((float*)C)[idx] = rv + v;
                } else if (OMODE == 1) {
                    ((bf16*)C)[idx] = __float2bfloat16(v);
                } else {
                    atomicAdd(&((float*)C)[idx], rowscale[(size_t)srow * rs_stride + e] * v);
                }
            }
        }
    }
}

// ---------------- MFMA flash attention with ALiBi, fixed-shift softmax ----------------
// block: 256 thr = 4 waves, each wave owns 32 q-rows (128 q-rows/block)
// reads packed QKV [tokens, 3072]; T14 async-stage; log2-domain softmax
__global__ __launch_bounds__(256) void attn_k(
    const bf16* __restrict__ QKV, bf16* __restrict__ Y)
{
    __shared__ bf16 Ks[64][72];
    __shared__ bf16 Vt[64][66];
    __shared__ bf16 Pw[4][32][72];
    const int t = threadIdx.x;
    const int wave = t >> 6, lane = t & 63;
    const int qm = lane & 15, quad = lane >> 4;
    const int b = blockIdx.z, h = blockIdx.y;
    const int qbase = blockIdx.x * 128 + wave * 32;
    const float LOG2E = 1.44269504f;
    const float slope2 = exp2f(-0.5f * (float)(h + 1)) * LOG2E;   // slope * log2(e)
    const float NEG8L2 = -11.54156036f;                            // -8 * log2(e)
    const float SCL2   = 0.18033688f;                              // 0.125 * log2(e)

    s8v qa[2][2];
    #pragma unroll
    for (int g = 0; g < 2; g++) {
        const bf16* qp = QKV + ((size_t)(b * SEQ + qbase + g * 16 + qm)) * QKV_S + h * HD;
        qa[g][0] = *(const s8v*)&qp[quad * 8];
        qa[g][1] = *(const s8v*)&qp[32 + quad * 8];
    }
    float aqp[2][4];
    #pragma unroll
    for (int g = 0; g < 2; g++)
        #pragma unroll
        for (int r = 0; r < 4; r++)
            aqp[g][r] = slope2 * (float)(qbase + g * 16 + quad * 4 + r) + NEG8L2;

    f32x4 o[2][4] = {};
    float l[2][4] = {};

    const int sr = t >> 2;
    const int scc = (t & 3) * 16;
    // base for this lane's K row slice; V is +1024 from K within the packed row
    const bf16* kvb = QKV + (size_t)(b * SEQ) * QKV_S + D_MODEL + h * HD + scc;

    {
        const bf16* p0 = kvb + (size_t)sr * QKV_S;
        s8v k0v = *(const s8v*)&p0[0];
        s8v k1v = *(const s8v*)&p0[8];
        s8v v0  = *(const s8v*)&p0[D_MODEL];
        s8v v1  = *(const s8v*)&p0[D_MODEL + 8];

        for (int k0 = 0; k0 < SEQ; k0 += 64) {
            *(s8v*)&Ks[sr][scc] = k0v;
            *(s8v*)&Ks[sr][scc + 8] = k1v;
            #pragma unroll
            for (int j = 0; j < 8; j++) {
                Vt[scc + j][sr]     = ((const bf16*)&v0)[j];
                Vt[scc + 8 + j][sr] = ((const bf16*)&v1)[j];
            }
            __syncthreads();
            if (k0 + 64 < SEQ) {   // T14: issue next tile's loads; latency hides under compute
                const bf16* np = kvb + (size_t)(k0 + 64 + sr) * QKV_S;
                k0v = *(const s8v*)&np[0];
                k1v = *(const s8v*)&np[8];
                v0  = *(const s8v*)&np[D_MODEL];
                v1  = *(const s8v*)&np[D_MODEL + 8];
            }
            float bk[4];
            #pragma unroll
            for (int jt = 0; jt < 4; jt++) bk[jt] = slope2 * (float)(k0 + jt * 16 + qm);
            #pragma unroll
            for (int g = 0; g < 2; g++) {
                f32x4 scr[4];
                #pragma unroll
                for (int jt = 0; jt < 4; jt++) {
                    f32x4 z = {};
                    s8v b0 = *(const s8v*)&Ks[jt * 16 + qm][quad * 8];
                    s8v b1 = *(const s8v*)&Ks[jt * 16 + qm][32 + quad * 8];
                    z = __builtin_amdgcn_mfma_f32_16x16x32_bf16(qa[g][0], b0, z, 0, 0, 0);
                    z = __builtin_amdgcn_mfma_f32_16x16x32_bf16(qa[g][1], b1, z, 0, 0, 0);
                    scr[jt] = z;
                }
                #pragma unroll
                for (int jt = 0; jt < 4; jt++) {
                    #pragma unroll
                    for (int r = 0; r < 4; r++) {
                        float term = fminf(aqp[g][r] - bk[jt], NEG8L2);
                        float pf = exp2f(fmaf(scr[jt][r], SCL2, term));
                        bf16 pb = __float2bfloat16(pf);
                        l[g][r] += __bfloat162float(pb);
                        Pw[wave][g * 16 + quad * 4 + r][jt * 16 + qm] = pb;
                    }
                }
            }
            __builtin_amdgcn_wave_barrier();
            #pragma unroll
            for (int g = 0; g < 2; g++) {
                s8v pa0 = *(const s8v*)&Pw[wave][g * 16 + qm][quad * 8];
                s8v pa1 = *(const s8v*)&Pw[wave][g * 16 + qm][32 + quad * 8];
                #pragma unroll
                for (int dt = 0; dt < 4; dt++) {
                    s8v vb0 = *(const s8v*)&Vt[dt * 16 + qm][quad * 8];
                    s8v vb1 = *(const s8v*)&Vt[dt * 16 + qm][32 + quad * 8];
                    o[g][dt] = __builtin_amdgcn_mfma_f32_16x16x32_bf16(pa0, vb0, o[g][dt], 0, 0, 0);
                    o[g][dt] = __builtin_amdgcn_mfma_f32_16x16x32_bf16(pa1, vb1, o[g][dt], 0, 0, 0);
                }
            }
            __syncthreads();
        }
    }
    #pragma unroll
    for (int g = 0; g < 2; g++)
        #pragma unroll
        for (int r = 0; r < 4; r++) {
            float s = l[g][r];
            s += __shfl_xor(s, 1); s += __shfl_xor(s, 2);
            s += __shfl_xor(s, 4); s += __shfl_xor(s, 8);
            l[g][r] = 1.0f / s;
        }
    #pragma unroll
    for (int g = 0; g < 2; g++)
        #pragma unroll
        for (int dt = 0; dt < 4; dt++)
            #pragma unroll
            for (int r = 0; r < 4; r++) {
                size_t idx = ((size_t)(b * SEQ + qbase + g * 16 + quad * 4 + r)) * D_MODEL + h * HD + dt * 16 + qm;
                Y[idx] = __float2bfloat16(o[g][dt][r] * l[g][r]);
            }
}

// ---------------- router: gates, top-2 weights, aux, per-expert token lists ----------------
__global__ __launch_bounds__(256) void router_k(
    const float* __restrict__ xf, const float* __restrict__ rw,
    float* __restrict__ wts, float* __restrict__ auxb,
    int* __restrict__ cnt, int* __restrict__ elist)
{
    const int wave = threadIdx.x >> 6, lane = threadIdx.x & 63;
    float4 w[4][4];
    #pragma unroll
    for (int e = 0; e < 4; e++)
        #pragma unroll
        for (int c = 0; c < 4; c++)
            w[e][c] = *(const float4*)&rw[e * D_MODEL + lane * 16 + c * 4];
    float ag[4] = {0.f, 0.f, 0.f, 0.f};
    float ac[4] = {0.f, 0.f, 0.f, 0.f};
    __shared__ int sel[16][2];
    __shared__ float sh[4][8];
    const int t0 = (blockIdx.x * 4 + wave) * 4;
    #pragma unroll
    for (int i = 0; i < 4; i++) {
        const int tk = t0 + i;
        const float* xr = xf + (size_t)tk * D_MODEL + lane * 16;
        float4 xv[4];
        #pragma unroll
        for (int c = 0; c < 4; c++) xv[c] = *(const float4*)&xr[c * 4];
        float p[4] = {0.f, 0.f, 0.f, 0.f};
        #pragma unroll
        for (int e = 0; e < 4; e++)
            #pragma unroll
            for (int c = 0; c < 4; c++) {
                p[e] = fmaf(xv[c].x, w[e][c].x, p[e]);
                p[e] = fmaf(xv[c].y, w[e][c].y, p[e]);
                p[e] = fmaf(xv[c].z, w[e][c].z, p[e]);
                p[e] = fmaf(xv[c].w, w[e][c].w, p[e]);
            }
        #pragma unroll
        for (int o = 1; o < 64; o <<= 1) {
            p[0] += __shfl_xor(p[0], o); p[1] += __shfl_xor(p[1], o);
            p[2] += __shfl_xor(p[2], o); p[3] += __shfl_xor(p[3], o);
        }
        float g[4];
        float mx = fmaxf(fmaxf(p[0], p[1]), fmaxf(p[2], p[3]));
        float se = 0.f;
        #pragma unroll
        for (int e = 0; e < 4; e++) { g[e] = __expf(p[e] - mx); se += g[e]; }
        #pragma unroll
        for (int e = 0; e < 4; e++) g[e] /= se;
        int i1 = 0; float v1 = g[0];
        #pragma unroll
        for (int e = 1; e < 4; e++) if (g[e] > v1) { v1 = g[e]; i1 = e; }
        int i2 = -1; float v2 = -1.f;
        #pragma unroll
        for (int e = 0; e < 4; e++) if (e != i1 && g[e] > v2) { v2 = g[e]; i2 = e; }
        float sw = fmaxf(v1 + v2, 1e-9f);
        if (lane < 4) {
            float wv = (lane == i1) ? v1 / sw : ((lane == i2) ? v2 / sw : 0.f);
            wts[(size_t)tk * 4 + lane] = wv;
        }
        if (lane == 0) {
            #pragma unroll
            for (int e = 0; e < 4; e++) ag[e] += g[e];
            ac[i1] += 1.f; ac[i2] += 1.f;
            sel[wave * 4 + i][0] = i1;
            sel[wave * 4 + i][1] = i2;
        }
    }
    if (lane == 0)
        #pragma unroll
        for (int e = 0; e < 4; e++) { sh[wave][e] = ag[e]; sh[wave][4 + e] = ac[e]; }
    __syncthreads();
    if (threadIdx.x < 8) {
        float s = sh[0][threadIdx.x] + sh[1][threadIdx.x] + sh[2][threadIdx.x] + sh[3][threadIdx.x];
        atomicAdd(&auxb[threadIdx.x], s);
    }
    if (threadIdx.x < 4) {
        const int e = threadIdx.x;
        int loc[16]; int c = 0;
        #pragma unroll
        for (int s = 0; s < 16; s++)
            if (sel[s][0] == e || sel[s][1] == e) loc[c++] = blockIdx.x * 16 + s;
        if (c) {
            int base = atomicAdd(&cnt[e], c);
            for (int k = 0; k < c; k++) elist[e * TOKENS + base + k] = loc[k];
        }
    }
}

// ---------------- final: out = x_s + depthwise-conv5(Tr) + tb ----------------
__global__ __launch_bounds__(256) void final_k(
    const float* __restrict__ xs, const float* __restrict__ Tr,
    const float* __restrict__ tw, const float* __restrict__ tb, float* __restrict__ out)
{
    int n = blockIdx.x, b = blockIdx.y, t = threadIdx.x;
    for (int d = t; d < D_MODEL; d += 256) {
        float acc = tb[d];
        #pragma unroll
        for (int j = 0; j < 5; j++) {
            int i = n + j - 2;
            if (i >= 0 && i < SEQ)
                acc += Tr[((size_t)(b * SEQ + i)) * D_MODEL + d] * tw[d * 5 + j];
        }
        size_t idx = ((size_t)(b * SEQ + n)) * D_MODEL + d;
        out[idx] = xs[idx] + acc;
    }
}

__global__ void aux_k(const float* __restrict__ ab, float* __restrict__ out) {
    if (threadIdx.x == 0 && blockIdx.x == 0) {
        float a = 0.f;
        for (int e = 0; e < 4; e++)
            a += (ab[e] / (float)TOKENS) * (ab[4 + e] / (float)TOKENS);
        out[0] = 4.0f * a;
    }
}

extern "C" void kernel_launch(void* const* d_in, const int* in_sizes, int n_in,
                              void* d_out, int out_size, void* d_ws, size_t ws_size,
                              hipStream_t stream)
{
    const float* x    = (const float*)d_in[0];
    const float* qw   = (const float*)d_in[1];
    const float* qb   = (const float*)d_in[2];
    const float* kw   = (const float*)d_in[3];
    const float* kb   = (const float*)d_in[4];
    const float* vw   = (const float*)d_in[5];
    const float* vb   = (const float*)d_in[6];
    const float* ow   = (const float*)d_in[7];
    const float* ob   = (const float*)d_in[8];
    const float* n1g  = (const float*)d_in[9];
    const float* n1b  = (const float*)d_in[10];
    const float* n2g  = (const float*)d_in[11];
    const float* n2b  = (const float*)d_in[12];
    const float* alpha= (const float*)d_in[13];
    const float* dw7  = (const float*)d_in[14];
    const float* dw25 = (const float*)d_in[15];
    const float* dw49 = (const float*)d_in[16];
    const float* rw   = (const float*)d_in[17];
    const float* ew1  = (const float*)d_in[18];
    const float* eb1  = (const float*)d_in[19];
    const float* ew2  = (const float*)d_in[20];
    const float* eb2  = (const float*)d_in[21];
    const float* tw   = (const float*)d_in[22];
    const float* tb   = (const float*)d_in[23];

    char* ws = (char*)d_ws;
    const size_t MBy = 1ull << 20;
    float* S    = (float*)(ws + 0 * MBy);
    float* Tr   = (float*)(ws + 32 * MBy);
    float* XF   = (float*)(ws + 64 * MBy);
    bf16*  SNB  = (bf16*)(ws + 96 * MBy);    // [8192,1024] bf16; also attn Y
    bf16*  QKVB = (bf16*)(ws + 112 * MBy);   // [8192, 3072] packed Q|K|V (112..160)
    bf16*  XFB  = (bf16*)(ws + 160 * MBy);
    bf16*  WQ   = (bf16*)(ws + 176 * MBy);   // WQ|WK|WV contiguous = fused [3072,1024]
    bf16*  WK   = (bf16*)(ws + 178 * MBy);
    bf16*  WV   = (bf16*)(ws + 180 * MBy);
    bf16*  WO   = (bf16*)(ws + 182 * MBy);
    bf16*  WE1  = (bf16*)(ws + 184 * MBy);
    bf16*  WE2  = (bf16*)(ws + 200 * MBy);
    float* WTS  = (float*)(ws + 216 * MBy);
    float* AUXB = (float*)(ws + 217 * MBy);           // 8 floats
    int*   CNT  = (int*)(AUXB + 8);                   // 4 ints
    int*   OFF  = CNT + 4;                            // 4 ints (prefix sums)
    float* QKVBIAS = (float*)(ws + 217 * MBy + 4096); // 3072 floats
    int*   ELST = (int*)(ws + 218 * MBy);             // 4 * 8192 ints
    bf16*  YB = SNB;
    // compact MoE hidden: 16384 rows x 2048 bf16 = 64 MiB, reuses dead SNB+QKVB (96..160)
    bf16*  HALL = (bf16*)(ws + 96 * MBy);

    f2b_k<<<2048, 256, 0, stream>>>(qw, WQ, D_MODEL * D_MODEL);
    f2b_k<<<2048, 256, 0, stream>>>(kw, WK, D_MODEL * D_MODEL);
    f2b_k<<<2048, 256, 0, stream>>>(vw, WV, D_MODEL * D_MODEL);
    f2b_k<<<2048, 256, 0, stream>>>(ow, WO, D_MODEL * D_MODEL);
    f2b_k<<<4096, 256, 0, stream>>>(ew1, WE1, 4 * MOE_H * D_MODEL);
    f2b_k<<<4096, 256, 0, stream>>>(ew2, WE2, 4 * D_MODEL * MOE_H);
    cat3_k<<<12, 256, 0, stream>>>(qb, kb, vb, QKVBIAS);

    decomp_k<<<dim3(SEQ / TN, D_MODEL / TD, NB), 256, 0, stream>>>(x, alpha, dw7, dw25, dw49, Tr, S);

    ln_k<<<TOKENS, 256, 0, stream>>>(S, n1g, n1b, SNB, nullptr);

    // fused QKV projection: [8192,1024] @ [3072,1024]^T -> [8192,3072]
    gemm_nt<0, 1, 0><<<dim3(64, 24), 512, 0, stream>>>(SNB, WQ, QKVBIAS, nullptr, nullptr, 0, QKVB, TOKENS, D_MODEL, QKV_S, nullptr, nullptr, nullptr, 0, 0);

    attn_k<<<dim3(SEQ / 128, NHEAD, NB), 256, 0, stream>>>(QKVB, YB);

    gemm_nt<0, 0, 0><<<dim3(64, 8), 512, 0, stream>>>(YB, WO, ob, S, nullptr, 0, S, TOKENS, D_MODEL, D_MODEL, nullptr, nullptr, nullptr, 0, 0);

    ln_k<<<TOKENS, 256, 0, stream>>>(S, n2g, n2b, XFB, XF);

    hipMemsetAsync(AUXB, 0, 64, stream);
    router_k<<<TOKENS / 16, 256, 0, stream>>>(XF, rw, WTS, AUXB, CNT, ELST);
    prefix_k<<<1, 64, 0, stream>>>(CNT, OFF);

    // sparse top-2 MoE, all experts batched via blockIdx.z
    // up: XFB gathered -> HALL compact (gelu);   down: HALL -> S (atomic scatter-add)
    gemm_nt<1, 1, 1><<<dim3(64, MOE_H / 128, 4), 512, 0, stream>>>(
        XFB, WE1, eb1, nullptr, nullptr, 0, HALL, TOKENS, D_MODEL, MOE_H,
        ELST, CNT, OFF, (size_t)MOE_H * D_MODEL, MOE_H);
    gemm_nt<0, 2, 2><<<dim3(64, D_MODEL / 128, 4), 512, 0, stream>>>(
        HALL, WE2, eb2, nullptr, WTS, 4, S, TOKENS, MOE_H, D_MODEL,
        ELST, CNT, OFF, (size_t)D_MODEL * MOE_H, D_MODEL);

    final_k<<<dim3(SEQ, NB), 256, 0, stream>>>(S, Tr, tw, tb, (float*)d_out);
    aux_k<<<1, 64, 0, stream>>>(AUXB, (float*)d_out + (out_size - 1));
}

// Round 8
// 856.390 us; speedup vs baseline: 1.3963x; 1.0025x over previous
//
#include <hip/hip_runtime.h>
#include <hip/hip_bf16.h>
#include <math.h>

using bf16 = __hip_bfloat16;
typedef __attribute__((ext_vector_type(8))) short s8v;
typedef __attribute__((ext_vector_type(4))) float f32x4;

#define D_MODEL 1024
#define NB 8
#define SEQ 1024
#define NHEAD 16
#define HD 64
#define MOE_H 2048
#define TOKENS (NB*SEQ)
#define QKV_S 3072   // fused QKV row stride

// ---------------- fp32 -> bf16 convert: all 6 weight tensors in one launch ----------------
__global__ void f2b_all(const float* __restrict__ s0, const float* __restrict__ s1,
                        const float* __restrict__ s2, const float* __restrict__ s3,
                        const float* __restrict__ s4, const float* __restrict__ s5,
                        bf16* __restrict__ d0, bf16* __restrict__ d1,
                        bf16* __restrict__ d2, bf16* __restrict__ d3,
                        bf16* __restrict__ d4, bf16* __restrict__ d5)
{
    const size_t M1 = 1024 * 1024;
    const size_t total = 4 * M1 + 8 * M1 + 8 * M1;   // 4 proj + ew1 + ew2
    for (size_t i = (size_t)blockIdx.x * blockDim.x + threadIdx.x; i < total;
         i += (size_t)gridDim.x * blockDim.x) {
        if (i < M1)            d0[i] = __float2bfloat16(s0[i]);
        else if (i < 2 * M1)   d1[i - M1] = __float2bfloat16(s1[i - M1]);
        else if (i < 3 * M1)   d2[i - 2 * M1] = __float2bfloat16(s2[i - 2 * M1]);
        else if (i < 4 * M1)   d3[i - 3 * M1] = __float2bfloat16(s3[i - 3 * M1]);
        else if (i < 12 * M1)  d4[i - 4 * M1] = __float2bfloat16(s4[i - 4 * M1]);
        else                   d5[i - 12 * M1] = __float2bfloat16(s5[i - 12 * M1]);
    }
}

// concat 3x1024 bias vectors into one 3072 buffer
__global__ void cat3_k(const float* __restrict__ a, const float* __restrict__ b,
                       const float* __restrict__ c, float* __restrict__ o) {
    int i = blockIdx.x * blockDim.x + threadIdx.x;
    if (i < 1024) o[i] = a[i];
    else if (i < 2048) o[i] = b[i - 1024];
    else if (i < 3072) o[i] = c[i - 2048];
}

// prefix sums of the 4 expert counts
__global__ void prefix_k(const int* __restrict__ cnt, int* __restrict__ off) {
    if (threadIdx.x == 0 && blockIdx.x == 0) {
        int s = 0;
        for (int e = 0; e < 4; e++) { off[e] = s; s += cnt[e]; }
    }
}

// ---------------- decomposition: trend + seasonal (LDS-tiled stencil) ----------------
#define TN 128
#define TD 64
__global__ __launch_bounds__(256) void decomp_k(
    const float* __restrict__ x, const float* __restrict__ alpha,
    const float* __restrict__ dw7, const float* __restrict__ dw25,
    const float* __restrict__ dw49, float* __restrict__ Tr, float* __restrict__ S)
{
    __shared__ float xs[TN + 48][TD];
    const int n0 = blockIdx.x * TN, d0 = blockIdx.y * TD, b = blockIdx.z;
    for (int i = threadIdx.x; i < (TN + 48) * (TD / 4); i += 256) {
        int r = i / (TD / 4), c4 = (i % (TD / 4)) * 4;
        int n = n0 + r - 24;
        if (n < 0) n = -n;
        if (n > SEQ - 1) n = 2 * (SEQ - 1) - n;
        *(float4*)&xs[r][c4] =
            *(const float4*)&x[((size_t)(b * SEQ + n)) * D_MODEL + d0 + c4];
    }
    float a0 = alpha[0], a1 = alpha[1], a2 = alpha[2];
    float mx = fmaxf(a0, fmaxf(a1, a2));
    float e0 = __expf(a0 - mx), e1 = __expf(a1 - mx), e2 = __expf(a2 - mx);
    float inv = 1.0f / (e0 + e1 + e2);
    float w7 = e0 * inv, w25 = e1 * inv, w49 = e2 * inv;
    const int dl = threadIdx.x & 63;
    const int nt = threadIdx.x >> 6;
    const int d = d0 + dl;
    float w[49];
    #pragma unroll
    for (int j = 0; j < 49; j++) {
        float v = w49 * dw49[d * 49 + j];
        if (j >= 12 && j < 37) v += w25 * dw25[d * 25 + j - 12];
        if (j >= 21 && j < 28) v += w7 * dw7[d * 7 + j - 21];
        w[j] = v;
    }
    __syncthreads();
    for (int nl = nt; nl < TN; nl += 4) {
        float acc = 0.f;
        #pragma unroll
        for (int j = 0; j < 49; j++) acc = fmaf(xs[nl + j][dl], w[j], acc);
        size_t idx = ((size_t)(b * SEQ + n0 + nl)) * D_MODEL + d;
        Tr[idx] = acc;
        S[idx] = xs[nl + 24][dl] - acc;
    }
}

// ---------------- LayerNorm (fp32 in, bf16 out, optional fp32 out) ----------------
__global__ __launch_bounds__(256) void ln_k(
    const float* __restrict__ x, const float* __restrict__ g, const float* __restrict__ b,
    bf16* __restrict__ ob, float* __restrict__ of)
{
    int row = blockIdx.x, t = threadIdx.x;
    const float* xr = x + (size_t)row * D_MODEL;
    float s = 0.f, s2 = 0.f;
    for (int d = t; d < D_MODEL; d += 256) { float v = xr[d]; s += v; s2 += v * v; }
    #pragma unroll
    for (int o = 32; o > 0; o >>= 1) { s += __shfl_down(s, o); s2 += __shfl_down(s2, o); }
    __shared__ float sh[8];
    int wid = t >> 6, lane = t & 63;
    if (lane == 0) { sh[wid] = s; sh[4 + wid] = s2; }
    __syncthreads();
    if (t == 0) {
        float ts = sh[0] + sh[1] + sh[2] + sh[3];
        float t2 = sh[4] + sh[5] + sh[6] + sh[7];
        float m = ts / D_MODEL;
        float var = t2 / D_MODEL - m * m;
        sh[0] = m; sh[1] = rsqrtf(var + 1e-5f);
    }
    __syncthreads();
    float m = sh[0], rs = sh[1];
    for (int d = t; d < D_MODEL; d += 256) {
        float v = (xr[d] - m) * rs * g[d] + b[d];
        ob[(size_t)row * D_MODEL + d] = __float2bfloat16(v);
        if (of) of[(size_t)row * D_MODEL + d] = v;
    }
}

// ---------------- bf16 MFMA GEMM: C[M,O] = A[M,K] @ B[O,K]^T (+bias)(+act) ----------------
// 512 threads = 8 waves; block tile 128x128; wave tile 32x64; acc[2][4]=32 regs.
// 2-phase pipeline: double-buffered LDS, raw s_barrier (NO vmcnt drain), 2-deep reg prefetch.
// OMODE 0: fp32 out (+resid), 1: bf16 out
// GMODE 0: dense; 1: gather A rows via row_map, store compact at off+row;
//          2: dense compact A at off, store compact at off+row (no atomics)
// GMODE!=0: blockIdx.z = expert.
template<int ACT, int OMODE, int GMODE>
__global__ __launch_bounds__(512, 4) void gemm_nt(
    const bf16* __restrict__ A, const bf16* __restrict__ B,
    const float* __restrict__ bias, const float* resid,
    void* C, int M, int K, int O,
    const int* __restrict__ row_map, const int* __restrict__ cnt_ptr,
    const int* __restrict__ off_ptr, size_t b_estride, int bias_estride)
{
    const int bm = blockIdx.x, bn = blockIdx.y;
    const int e = (GMODE != 0) ? blockIdx.z : 0;
    int M_act = M;
    int off = 0;
    const int* rmap = row_map;
    if (GMODE != 0) {
        M_act = cnt_ptr[e];
        if (bm * 128 >= M_act) return;
        off = off_ptr[e];
        if (GMODE == 1) rmap = row_map + e * TOKENS;
        B += (size_t)e * b_estride;
        if (bias) bias += (size_t)e * bias_estride;
    }
    __shared__ bf16 As[2][128][72];
    __shared__ bf16 Bs[2][128][72];
    const int t = threadIdx.x;
    const int lane = t & 63, wid = t >> 6;   // wid 0..7
    const int wm = wid >> 1, wn = wid & 1;   // wm: 32-row strip, wn: 64-col strip
    f32x4 acc[2][4] = {};
    const int lr = t >> 3;          // 0..63
    const int lc = (t & 7) * 8;     // 0..56
    const size_t abase = (GMODE == 2) ? (size_t)(off + bm * 128) * K : (size_t)(bm * 128) * K;
    const size_t bbase = (size_t)(bn * 128) * K;
    size_t arow[2];
    #pragma unroll
    for (int p = 0; p < 2; p++) {
        int r = p * 64 + lr;
        if (GMODE == 1) {
            int gr = bm * 128 + r;
            arow[p] = (size_t)rmap[gr < M_act ? gr : M_act - 1] * K;
        } else {
            arow[p] = abase + (size_t)r * K;
        }
    }
    const int nt = K / 64;   // always even here

#define LOADT(RA, RB, TT) do { const int kn_ = (TT) * 64 + lc;                      \
    _Pragma("unroll") for (int p_ = 0; p_ < 2; p_++) {                              \
        RA[p_] = *(const s8v*)&A[arow[p_] + kn_];                                   \
        RB[p_] = *(const s8v*)&B[bbase + (size_t)(p_ * 64 + lr) * K + kn_]; } } while (0)
#define WRITET(BUF, RA, RB) do {                                                    \
    _Pragma("unroll") for (int p_ = 0; p_ < 2; p_++) {                              \
        *(s8v*)&As[BUF][p_ * 64 + lr][lc] = RA[p_];                                 \
        *(s8v*)&Bs[BUF][p_ * 64 + lr][lc] = RB[p_]; } } while (0)
#define LBAR() do { asm volatile("s_waitcnt lgkmcnt(0)" ::: "memory");              \
    __builtin_amdgcn_sched_barrier(0); __builtin_amdgcn_s_barrier(); } while (0)
#define COMPUTE(BUF) do {                                                           \
    _Pragma("unroll") for (int kk_ = 0; kk_ < 64; kk_ += 32) {                      \
        s8v af_[2], bf_[4];                                                         \
        _Pragma("unroll") for (int i_ = 0; i_ < 2; i_++)                            \
            af_[i_] = *(const s8v*)&As[BUF][wm * 32 + i_ * 16 + fr][kk_ + fq];      \
        _Pragma("unroll") for (int j_ = 0; j_ < 4; j_++)                            \
            bf_[j_] = *(const s8v*)&Bs[BUF][wn * 64 + j_ * 16 + fr][kk_ + fq];      \
        _Pragma("unroll") for (int i_ = 0; i_ < 2; i_++)                            \
            _Pragma("unroll") for (int j_ = 0; j_ < 4; j_++)                        \
                acc[i_][j_] = __builtin_amdgcn_mfma_f32_16x16x32_bf16(af_[i_], bf_[j_], acc[i_][j_], 0, 0, 0); \
    } } while (0)

    const int fr = lane & 15, fq = (lane >> 4) * 8;
    // pipeline regs: r0 = even tiles, r1 = odd tiles (static names, rule #20)
    s8v r0a[2], r0b[2], r1a[2], r1b[2];
    LOADT(r0a, r0b, 0);
    WRITET(0, r0a, r0b);
    LOADT(r1a, r1b, 1);   // issued before r0's tile-2 loads: consumed first
    LOADT(r0a, r0b, 2);
    LBAR();               // buf0 visible to all waves; prefetches stay in flight

    for (int tt = 0; tt < nt; tt += 2) {
        // even step: stage tile tt+1 -> buf1, prefetch tile tt+3, compute buf0
        WRITET(1, r1a, r1b);                       // counted vmcnt wait for r1 only
        if (tt + 3 < nt) LOADT(r1a, r1b, tt + 3);
        COMPUTE(0);
        LBAR();
        // odd step: stage tile tt+2 -> buf0, prefetch tile tt+4, compute buf1
        if (tt + 2 < nt) {
            WRITET(0, r0a, r0b);
            if (tt + 4 < nt) LOADT(r0a, r0b, tt + 4);
        }
        COMPUTE(1);
        LBAR();
    }
#undef LOADT
#undef WRITET
#undef LBAR
#undef COMPUTE

    const int cr = lane & 15, quad = lane >> 4;
    #pragma unroll
    for (int i = 0; i < 2; i++) {
        #pragma unroll
        for (int r = 0; r < 4; r++) {
            int row = bm * 128 + wm * 32 + i * 16 + quad * 4 + r;
            if (GMODE != 0 && row >= M_act) continue;
            int srow = (GMODE != 0) ? off + row : row;
            #pragma unroll
            for (int j = 0; j < 4; j++) {
                int col = bn * 128 + wn * 64 + j * 16 + cr;
                float v = acc[i][j][r];
                if (bias) v += bias[col];
                if (ACT == 1) v = 0.5f * v * (1.0f + erff(v * 0.70710678118f));
                size_t idx = (size_t)srow * O + col;
                if (OMODE == 0) {
                    float rv = resid ? resid[idx] : 0.0f;
                    ((float*)C)[idx] = rv + v;
                } else {
                    ((bf16*)C)[idx] = __float2bfloat16(v);
                }
            }
        }
    }
}

// ---------------- MoE combine: S[t] += w0*H[slot0] + w1*H[slot1] ----------------
__global__ __launch_bounds__(256) void combine_k(
    const bf16* __restrict__ H, const int* __restrict__ rev,
    const int* __restrict__ offp, const float* __restrict__ wts,
    float* __restrict__ S)
{
    const int tk = blockIdx.x, t = threadIdx.x;
    const int r0 = rev[tk * 2], r1 = rev[tk * 2 + 1];
    const int e0 = r0 >> 13, e1 = r1 >> 13;
    const float w0 = wts[tk * 4 + e0], w1 = wts[tk * 4 + e1];
    const bf16* h0 = H + (size_t)(offp[e0] + (r0 & 8191)) * D_MODEL;
    const bf16* h1 = H + (size_t)(offp[e1] + (r1 & 8191)) * D_MODEL;
    float* sr = S + (size_t)tk * D_MODEL;
    const int d = t * 4;
    ushort4 a = *(const ushort4*)&h0[d];
    ushort4 b = *(const ushort4*)&h1[d];
    float4 sv = *(float4*)&sr[d];
    sv.x += w0 * __bfloat162float(*(const bf16*)&a.x) + w1 * __bfloat162float(*(const bf16*)&b.x);
    sv.y += w0 * __bfloat162float(*(const bf16*)&a.y) + w1 * __bfloat162float(*(const bf16*)&b.y);
    sv.z += w0 * __bfloat162float(*(const bf16*)&a.z) + w1 * __bfloat162float(*(const bf16*)&b.z);
    sv.w += w0 * __bfloat162float(*(const bf16*)&a.w) + w1 * __bfloat162float(*(const bf16*)&b.w);
    *(float4*)&sr[d] = sv;
}

// ---------------- MFMA flash attention with ALiBi, fixed-shift softmax ----------------
__global__ __launch_bounds__(256) void attn_k(
    const bf16* __restrict__ QKV, bf16* __restrict__ Y)
{
    __shared__ bf16 Ks[64][72];
    __shared__ bf16 Vt[64][66];
    __shared__ bf16 Pw[4][32][72];
    const int t = threadIdx.x;
    const int wave = t >> 6, lane = t & 63;
    const int qm = lane & 15, quad = lane >> 4;
    const int b = blockIdx.z, h = blockIdx.y;
    const int qbase = blockIdx.x * 128 + wave * 32;
    const float LOG2E = 1.44269504f;
    const float slope2 = exp2f(-0.5f * (float)(h + 1)) * LOG2E;   // slope * log2(e)
    const float NEG8L2 = -11.54156036f;                            // -8 * log2(e)
    const float SCL2   = 0.18033688f;                              // 0.125 * log2(e)

    s8v qa[2][2];
    #pragma unroll
    for (int g = 0; g < 2; g++) {
        const bf16* qp = QKV + ((size_t)(b * SEQ + qbase + g * 16 + qm)) * QKV_S + h * HD;
        qa[g][0] = *(const s8v*)&qp[quad * 8];
        qa[g][1] = *(const s8v*)&qp[32 + quad * 8];
    }
    float aqp[2][4];
    #pragma unroll
    for (int g = 0; g < 2; g++)
        #pragma unroll
        for (int r = 0; r < 4; r++)
            aqp[g][r] = slope2 * (float)(qbase + g * 16 + quad * 4 + r) + NEG8L2;

    f32x4 o[2][4] = {};
    float l[2][4] = {};

    const int sr = t >> 2;
    const int scc = (t & 3) * 16;
    const bf16* kvb = QKV + (size_t)(b * SEQ) * QKV_S + D_MODEL + h * HD + scc;

    {
        const bf16* p0 = kvb + (size_t)sr * QKV_S;
        s8v k0v = *(const s8v*)&p0[0];
        s8v k1v = *(const s8v*)&p0[8];
        s8v v0  = *(const s8v*)&p0[D_MODEL];
        s8v v1  = *(const s8v*)&p0[D_MODEL + 8];

        for (int k0 = 0; k0 < SEQ; k0 += 64) {
            *(s8v*)&Ks[sr][scc] = k0v;
            *(s8v*)&Ks[sr][scc + 8] = k1v;
            #pragma unroll
            for (int j = 0; j < 8; j++) {
                Vt[scc + j][sr]     = ((const bf16*)&v0)[j];
                Vt[scc + 8 + j][sr] = ((const bf16*)&v1)[j];
            }
            __syncthreads();
            if (k0 + 64 < SEQ) {   // T14: issue next tile's loads
                const bf16* np = kvb + (size_t)(k0 + 64 + sr) * QKV_S;
                k0v = *(const s8v*)&np[0];
                k1v = *(const s8v*)&np[8];
                v0  = *(const s8v*)&np[D_MODEL];
                v1  = *(const s8v*)&np[D_MODEL + 8];
            }
            float bk[4];
            #pragma unroll
            for (int jt = 0; jt < 4; jt++) bk[jt] = slope2 * (float)(k0 + jt * 16 + qm);
            #pragma unroll
            for (int g = 0; g < 2; g++) {
                f32x4 scr[4];
                #pragma unroll
                for (int jt = 0; jt < 4; jt++) {
                    f32x4 z = {};
                    s8v b0 = *(const s8v*)&Ks[jt * 16 + qm][quad * 8];
                    s8v b1 = *(const s8v*)&Ks[jt * 16 + qm][32 + quad * 8];
                    z = __builtin_amdgcn_mfma_f32_16x16x32_bf16(qa[g][0], b0, z, 0, 0, 0);
                    z = __builtin_amdgcn_mfma_f32_16x16x32_bf16(qa[g][1], b1, z, 0, 0, 0);
                    scr[jt] = z;
                }
                #pragma unroll
                for (int jt = 0; jt < 4; jt++) {
                    #pragma unroll
                    for (int r = 0; r < 4; r++) {
                        float term = fminf(aqp[g][r] - bk[jt], NEG8L2);
                        float pf = exp2f(fmaf(scr[jt][r], SCL2, term));
                        bf16 pb = __float2bfloat16(pf);
                        l[g][r] += __bfloat162float(pb);
                        Pw[wave][g * 16 + quad * 4 + r][jt * 16 + qm] = pb;
                    }
                }
            }
            __builtin_amdgcn_wave_barrier();
            #pragma unroll
            for (int g = 0; g < 2; g++) {
                s8v pa0 = *(const s8v*)&Pw[wave][g * 16 + qm][quad * 8];
                s8v pa1 = *(const s8v*)&Pw[wave][g * 16 + qm][32 + quad * 8];
                #pragma unroll
                for (int dt = 0; dt < 4; dt++) {
                    s8v vb0 = *(const s8v*)&Vt[dt * 16 + qm][quad * 8];
                    s8v vb1 = *(const s8v*)&Vt[dt * 16 + qm][32 + quad * 8];
                    o[g][dt] = __builtin_amdgcn_mfma_f32_16x16x32_bf16(pa0, vb0, o[g][dt], 0, 0, 0);
                    o[g][dt] = __builtin_amdgcn_mfma_f32_16x16x32_bf16(pa1, vb1, o[g][dt], 0, 0, 0);
                }
            }
            __syncthreads();
        }
    }
    #pragma unroll
    for (int g = 0; g < 2; g++)
        #pragma unroll
        for (int r = 0; r < 4; r++) {
            float s = l[g][r];
            s += __shfl_xor(s, 1); s += __shfl_xor(s, 2);
            s += __shfl_xor(s, 4); s += __shfl_xor(s, 8);
            l[g][r] = 1.0f / s;
        }
    #pragma unroll
    for (int g = 0; g < 2; g++)
        #pragma unroll
        for (int dt = 0; dt < 4; dt++)
            #pragma unroll
            for (int r = 0; r < 4; r++) {
                size_t idx = ((size_t)(b * SEQ + qbase + g * 16 + quad * 4 + r)) * D_MODEL + h * HD + dt * 16 + qm;
                Y[idx] = __float2bfloat16(o[g][dt][r] * l[g][r]);
            }
}

// ---------------- router: gates, top-2 weights, aux, expert lists + reverse map ----------------
__global__ __launch_bounds__(256) void router_k(
    const float* __restrict__ xf, const float* __restrict__ rw,
    float* __restrict__ wts, float* __restrict__ auxb,
    int* __restrict__ cnt, int* __restrict__ elist, int* __restrict__ rev)
{
    const int wave = threadIdx.x >> 6, lane = threadIdx.x & 63;
    float4 w[4][4];
    #pragma unroll
    for (int e = 0; e < 4; e++)
        #pragma unroll
        for (int c = 0; c < 4; c++)
            w[e][c] = *(const float4*)&rw[e * D_MODEL + lane * 16 + c * 4];
    float ag[4] = {0.f, 0.f, 0.f, 0.f};
    float ac[4] = {0.f, 0.f, 0.f, 0.f};
    __shared__ int sel[16][2];
    __shared__ float sh[4][8];
    const int t0 = (blockIdx.x * 4 + wave) * 4;
    #pragma unroll
    for (int i = 0; i < 4; i++) {
        const int tk = t0 + i;
        const float* xr = xf + (size_t)tk * D_MODEL + lane * 16;
        float4 xv[4];
        #pragma unroll
        for (int c = 0; c < 4; c++) xv[c] = *(const float4*)&xr[c * 4];
        float p[4] = {0.f, 0.f, 0.f, 0.f};
        #pragma unroll
        for (int e = 0; e < 4; e++)
            #pragma unroll
            for (int c = 0; c < 4; c++) {
                p[e] = fmaf(xv[c].x, w[e][c].x, p[e]);
                p[e] = fmaf(xv[c].y, w[e][c].y, p[e]);
                p[e] = fmaf(xv[c].z, w[e][c].z, p[e]);
                p[e] = fmaf(xv[c].w, w[e][c].w, p[e]);
            }
        #pragma unroll
        for (int o = 1; o < 64; o <<= 1) {
            p[0] += __shfl_xor(p[0], o); p[1] += __shfl_xor(p[1], o);
            p[2] += __shfl_xor(p[2], o); p[3] += __shfl_xor(p[3], o);
        }
        float g[4];
        float mx = fmaxf(fmaxf(p[0], p[1]), fmaxf(p[2], p[3]));
        float se = 0.f;
        #pragma unroll
        for (int e = 0; e < 4; e++) { g[e] = __expf(p[e] - mx); se += g[e]; }
        #pragma unroll
        for (int e = 0; e < 4; e++) g[e] /= se;
        int i1 = 0; float v1 = g[0];
        #pragma unroll
        for (int e = 1; e < 4; e++) if (g[e] > v1) { v1 = g[e]; i1 = e; }
        int i2 = -1; float v2 = -1.f;
        #pragma unroll
        for (int e = 0; e < 4; e++) if (e != i1 && g[e] > v2) { v2 = g[e]; i2 = e; }
        float sw = fmaxf(v1 + v2, 1e-9f);
        if (lane < 4) {
            float wv = (lane == i1) ? v1 / sw : ((lane == i2) ? v2 / sw : 0.f);
            wts[(size_t)tk * 4 + lane] = wv;
        }
        if (lane == 0) {
            #pragma unroll
            for (int e = 0; e < 4; e++) ag[e] += g[e];
            ac[i1] += 1.f; ac[i2] += 1.f;
            sel[wave * 4 + i][0] = i1;
            sel[wave * 4 + i][1] = i2;
        }
    }
    if (lane == 0)
        #pragma unroll
        for (int e = 0; e < 4; e++) { sh[wave][e] = ag[e]; sh[wave][4 + e] = ac[e]; }
    __syncthreads();
    if (threadIdx.x < 8) {
        float s = sh[0][threadIdx.x] + sh[1][threadIdx.x] + sh[2][threadIdx.x] + sh[3][threadIdx.x];
        atomicAdd(&auxb[threadIdx.x], s);
    }
    if (threadIdx.x < 4) {
        const int e = threadIdx.x;
        int loc[16]; int c = 0;
        #pragma unroll
        for (int s = 0; s < 16; s++)
            if (sel[s][0] == e || sel[s][1] == e) loc[c++] = s;
        if (c) {
            int base = atomicAdd(&cnt[e], c);
            for (int k = 0; k < c; k++) {
                int s = loc[k];
                int tok = blockIdx.x * 16 + s;
                elist[e * TOKENS + base + k] = tok;
                int slot = (sel[s][0] == e) ? 0 : 1;
                rev[tok * 2 + slot] = (e << 13) | (base + k);
            }
        }
    }
}

// ---------------- final: out = x_s + depthwise-conv5(Tr) + tb ----------------
__global__ __launch_bounds__(256) void final_k(
    const float* __restrict__ xs, const float* __restrict__ Tr,
    const float* __restrict__ tw, const float* __restrict__ tb, float* __restrict__ out)
{
    int n = blockIdx.x, b = blockIdx.y, t = threadIdx.x;
    for (int d = t; d < D_MODEL; d += 256) {
        float acc = tb[d];
        #pragma unroll
        for (int j = 0; j < 5; j++) {
            int i = n + j - 2;
            if (i >= 0 && i < SEQ)
                acc += Tr[((size_t)(b * SEQ + i)) * D_MODEL + d] * tw[d * 5 + j];
        }
        size_t idx = ((size_t)(b * SEQ + n)) * D_MODEL + d;
        out[idx] = xs[idx] + acc;
    }
}

__global__ void aux_k(const float* __restrict__ ab, float* __restrict__ out) {
    if (threadIdx.x == 0 && blockIdx.x == 0) {
        float a = 0.f;
        for (int e = 0; e < 4; e++)
            a += (ab[e] / (float)TOKENS) * (ab[4 + e] / (float)TOKENS);
        out[0] = 4.0f * a;
    }
}

extern "C" void kernel_launch(void* const* d_in, const int* in_sizes, int n_in,
                              void* d_out, int out_size, void* d_ws, size_t ws_size,
                              hipStream_t stream)
{
    const float* x    = (const float*)d_in[0];
    const float* qw   = (const float*)d_in[1];
    const float* qb   = (const float*)d_in[2];
    const float* kw   = (const float*)d_in[3];
    const float* kb   = (const float*)d_in[4];
    const float* vw   = (const float*)d_in[5];
    const float* vb   = (const float*)d_in[6];
    const float* ow   = (const float*)d_in[7];
    const float* ob   = (const float*)d_in[8];
    const float* n1g  = (const float*)d_in[9];
    const float* n1b  = (const float*)d_in[10];
    const float* n2g  = (const float*)d_in[11];
    const float* n2b  = (const float*)d_in[12];
    const float* alpha= (const float*)d_in[13];
    const float* dw7  = (const float*)d_in[14];
    const float* dw25 = (const float*)d_in[15];
    const float* dw49 = (const float*)d_in[16];
    const float* rw   = (const float*)d_in[17];
    const float* ew1  = (const float*)d_in[18];
    const float* eb1  = (const float*)d_in[19];
    const float* ew2  = (const float*)d_in[20];
    const float* eb2  = (const float*)d_in[21];
    const float* tw   = (const float*)d_in[22];
    const float* tb   = (const float*)d_in[23];

    char* ws = (char*)d_ws;
    const size_t MBy = 1ull << 20;
    float* S    = (float*)(ws + 0 * MBy);
    float* Tr   = (float*)(ws + 32 * MBy);
    float* XF   = (float*)(ws + 64 * MBy);   // f32 LN-out for router; dead after router
    bf16*  HOUT = (bf16*)(ws + 64 * MBy);    // [16384,1024] bf16 compact expert outs (reuses XF)
    bf16*  SNB  = (bf16*)(ws + 96 * MBy);    // [8192,1024] bf16; also attn Y
    bf16*  QKVB = (bf16*)(ws + 112 * MBy);   // [8192, 3072] packed Q|K|V (112..160)
    bf16*  XFB  = (bf16*)(ws + 160 * MBy);
    bf16*  WQ   = (bf16*)(ws + 176 * MBy);   // WQ|WK|WV contiguous = fused [3072,1024]
    bf16*  WK   = (bf16*)(ws + 178 * MBy);
    bf16*  WV   = (bf16*)(ws + 180 * MBy);
    bf16*  WO   = (bf16*)(ws + 182 * MBy);
    bf16*  WE1  = (bf16*)(ws + 184 * MBy);
    bf16*  WE2  = (bf16*)(ws + 200 * MBy);
    float* WTS  = (float*)(ws + 216 * MBy);
    float* AUXB = (float*)(ws + 217 * MBy);           // 8 floats
    int*   CNT  = (int*)(AUXB + 8);                   // 4 ints
    int*   OFF  = CNT + 4;                            // 4 ints (prefix sums)
    float* QKVBIAS = (float*)(ws + 217 * MBy + 4096); // 3072 floats
    int*   ELST = (int*)(ws + 218 * MBy);             // 4 * 8192 ints (128 KB)
    int*   REV  = (int*)(ws + 218 * MBy + 131072);    // 8192 * 2 ints (64 KB)
    bf16*  YB = SNB;
    // compact MoE hidden: 16384 rows x 2048 bf16 = 64 MiB, reuses dead SNB+QKVB (96..160)
    bf16*  HALL = (bf16*)(ws + 96 * MBy);

    f2b_all<<<4096, 256, 0, stream>>>(qw, kw, vw, ow, ew1, ew2, WQ, WK, WV, WO, WE1, WE2);
    cat3_k<<<12, 256, 0, stream>>>(qb, kb, vb, QKVBIAS);

    decomp_k<<<dim3(SEQ / TN, D_MODEL / TD, NB), 256, 0, stream>>>(x, alpha, dw7, dw25, dw49, Tr, S);

    ln_k<<<TOKENS, 256, 0, stream>>>(S, n1g, n1b, SNB, nullptr);

    // fused QKV projection: [8192,1024] @ [3072,1024]^T -> [8192,3072]
    gemm_nt<0, 1, 0><<<dim3(64, 24), 512, 0, stream>>>(SNB, WQ, QKVBIAS, nullptr, QKVB, TOKENS, D_MODEL, QKV_S, nullptr, nullptr, nullptr, 0, 0);

    attn_k<<<dim3(SEQ / 128, NHEAD, NB), 256, 0, stream>>>(QKVB, YB);

    gemm_nt<0, 0, 0><<<dim3(64, 8), 512, 0, stream>>>(YB, WO, ob, S, S, TOKENS, D_MODEL, D_MODEL, nullptr, nullptr, nullptr, 0, 0);

    ln_k<<<TOKENS, 256, 0, stream>>>(S, n2g, n2b, XFB, XF);

    hipMemsetAsync(AUXB, 0, 64, stream);
    router_k<<<TOKENS / 16, 256, 0, stream>>>(XF, rw, WTS, AUXB, CNT, ELST, REV);
    prefix_k<<<1, 64, 0, stream>>>(CNT, OFF);

    // sparse top-2 MoE, all experts batched via blockIdx.z, no atomics:
    // up: XFB gathered -> HALL compact (gelu); down: HALL -> HOUT compact bf16 (+bias);
    // combine: S += w0*HOUT[slot0] + w1*HOUT[slot1]
    gemm_nt<1, 1, 1><<<dim3(64, MOE_H / 128, 4), 512, 0, stream>>>(
        XFB, WE1, eb1, nullptr, HALL, TOKENS, D_MODEL, MOE_H,
        ELST, CNT, OFF, (size_t)MOE_H * D_MODEL, MOE_H);
    gemm_nt<0, 1, 2><<<dim3(64, D_MODEL / 128, 4), 512, 0, stream>>>(
        HALL, WE2, eb2, nullptr, HOUT, TOKENS, MOE_H, D_MODEL,
        nullptr, CNT, OFF, (size_t)D_MODEL * MOE_H, D_MODEL);
    combine_k<<<TOKENS, 256, 0, stream>>>(HOUT, REV, OFF, WTS, S);

    final_k<<<dim3(SEQ, NB), 256, 0, stream>>>(S, Tr, tw, tb, (float*)d_out);
    aux_k<<<1, 64, 0, stream>>>(AUXB, (float*)d_out + (out_size - 1));
}